// Round 8
// baseline (656.771 us; speedup 1.0000x reference)
//
#include <hip/hip_runtime.h>
#include <hip/hip_bf16.h>
#include <cstdint>
#include <cstddef>

#define HW     16384      // H*W
#define WIDTH  128
#define NB     2
#define NTOPK  300
#define JUNC_TH 0.008f

typedef __attribute__((ext_vector_type(8))) short s16x8;
typedef __attribute__((ext_vector_type(4))) float f32x4;

// ---------------------------------------------------------------- utilities
__device__ __forceinline__ float sigm(float x) { return 1.0f / (1.0f + expf(-x)); }

__device__ __forceinline__ unsigned short f2bf(float f) {
  __hip_bfloat16 h = __float2bfloat16(f);
  return __hip_bfloat16_raw(h).x;
}
__device__ __forceinline__ float bf2f(unsigned short u) {
  __hip_bfloat16_raw r; r.x = u;
  return __bfloat162float(__hip_bfloat16(r));
}
__device__ __forceinline__ float2 bf2x2(unsigned int u) {
  return make_float2(__uint_as_float(u << 16), __uint_as_float(u & 0xffff0000u));
}

#define GLOAD_LDS16(gp, lp)                                                        \
  __builtin_amdgcn_global_load_lds((const __attribute__((address_space(1))) void*)(gp), \
                                   (__attribute__((address_space(3))) void*)(lp), 16, 0, 0)

// XCD-cohort swizzle (kept from R7: FETCH 139->51 MB).
__device__ __forceinline__ void fc_tile_map(int bid, int nm, int& m_idx, int& n_idx) {
  if ((nm & 7) == 0) {
    int x = bid & 7;
    int k = bid >> 3;
    m_idx = x * (nm >> 3) + (k >> 3);
    n_idx = k & 7;
  } else {
    m_idx = bid >> 3;
    n_idx = bid & 7;
  }
}

// ---------------------------------------------------------------- W transpose (256x128 <- 128x256), fp32
__global__ void k_transpose_w(const float* __restrict__ w, float* __restrict__ wt) {
  int i = blockIdx.x * 256 + threadIdx.x;   // 32768
  int d = i & 127, c = i >> 7;
  wt[c * 128 + d] = w[d * 256 + c];
}

// ---------------------------------------------------------------- FC weight transpose+cast: wt_bf16[n][k] = w[k][n]
__global__ __launch_bounds__(256) void k_wtrans(const float* __restrict__ w,
                                                unsigned short* __restrict__ wt) {
  __shared__ float tile[32][33];
  int n0 = blockIdx.x * 32, k0 = blockIdx.y * 32;
  int tx = threadIdx.x & 31, ty = threadIdx.x >> 5;   // 32 x 8
#pragma unroll
  for (int r = 0; r < 32; r += 8)
    tile[ty + r][tx] = w[(size_t)(k0 + ty + r) * 1024 + n0 + tx];
  __syncthreads();
#pragma unroll
  for (int r = 0; r < 32; r += 8)
    wt[(size_t)(n0 + ty + r) * 1024 + k0 + tx] = f2bf(tile[tx][ty + r]);
}

// ---------------------------------------------------------------- loi GEMM (fp32 math, bf16 store): loi_t[b][p][d]
__global__ __launch_bounds__(256) void k_loi(const float* __restrict__ F,
                                             const float* __restrict__ wt,
                                             const float* __restrict__ bias,
                                             unsigned short* __restrict__ loi) {
  int b = blockIdx.y;
  int p0 = blockIdx.x * 64;
  __shared__ float As[8][64];
  __shared__ float Bs[8][128];
  int t = threadIdx.x;
  int tn = t & 15;    // n group: n = tn*8
  int tm = t >> 4;    // m group: m = tm*4
  float acc[4][8];
#pragma unroll
  for (int i = 0; i < 4; ++i)
#pragma unroll
    for (int j = 0; j < 8; ++j) acc[i][j] = 0.0f;

  const float* Fb = F + (size_t)b * 256 * HW;
  for (int c0 = 0; c0 < 256; c0 += 8) {
    __syncthreads();
    if (t < 128) {
      int kk = t >> 4, mv = t & 15;
      float4 v = *(const float4*)(Fb + (size_t)(c0 + kk) * HW + p0 + mv * 4);
      *(float4*)&As[kk][mv * 4] = v;
    }
    {
      int kk = t >> 5, dv = t & 31;
      float4 v = *(const float4*)(wt + (size_t)(c0 + kk) * 128 + dv * 4);
      *(float4*)&Bs[kk][dv * 4] = v;
    }
    __syncthreads();
#pragma unroll
    for (int kk = 0; kk < 8; ++kk) {
      float4 a4 = *(const float4*)&As[kk][tm * 4];
      float4 b0 = *(const float4*)&Bs[kk][tn * 8];
      float4 b1 = *(const float4*)&Bs[kk][tn * 8 + 4];
      float av[4] = {a4.x, a4.y, a4.z, a4.w};
      float bv[8] = {b0.x, b0.y, b0.z, b0.w, b1.x, b1.y, b1.z, b1.w};
#pragma unroll
      for (int i = 0; i < 4; ++i)
#pragma unroll
        for (int j = 0; j < 8; ++j) acc[i][j] += av[i] * bv[j];
    }
  }
  float4 c0v = *(const float4*)(bias + tn * 8);
  float4 c1v = *(const float4*)(bias + tn * 8 + 4);
  float bb[8] = {c0v.x, c0v.y, c0v.z, c0v.w, c1v.x, c1v.y, c1v.z, c1v.w};
#pragma unroll
  for (int i = 0; i < 4; ++i) {
    int p = p0 + tm * 4 + i;
    alignas(16) unsigned short o[8];
#pragma unroll
    for (int j = 0; j < 8; ++j) o[j] = f2bf(acc[i][j] + bb[j]);
    *(s16x8*)(loi + ((size_t)b * HW + p) * 128 + tn * 8) = *(const s16x8*)o;
  }
}

// ---------------------------------------------------------------- jloc = softmax(out9[5:7])[1]
__global__ void k_jloc(const float* __restrict__ out9, float* __restrict__ jloc) {
  int i = blockIdx.x * 256 + threadIdx.x;    // NB*HW
  int b = i >> 14, p = i & (HW - 1);
  const float* base = out9 + (size_t)b * 9 * HW;
  float o5 = base[5 * HW + p], o6 = base[6 * HW + p];
  float m = fmaxf(o5, o6);
  float e5 = expf(o5 - m), e6 = expf(o6 - m);
  jloc[i] = e6 / (e5 + e6);
}

// ---------------------------------------------------------------- NMS + sortable key
__global__ void k_nmskey(const float* __restrict__ jloc, unsigned long long* __restrict__ keys) {
  int i = blockIdx.x * 256 + threadIdx.x;
  int b = i >> 14, p = i & (HW - 1);
  int y = p >> 7, x = p & 127;
  const float* J = jloc + (size_t)b * HW;
  float c = J[p];
  float m = c;
  for (int dy = -1; dy <= 1; ++dy) {
    int yy = y + dy;
    if (yy < 0 || yy > 127) continue;
    for (int dx = -1; dx <= 1; ++dx) {
      int xx = x + dx;
      if (xx < 0 || xx > 127) continue;
      m = fmaxf(m, J[yy * WIDTH + xx]);
    }
  }
  unsigned int vb = (c == m) ? __float_as_uint(c) : 0u;   // jloc > 0 always -> bits monotone
  keys[i] = ((unsigned long long)vb << 32) | (unsigned int)(~p);
}

// ---------------------------------------------------------------- top-300 per image via bitonic sort (1 block/image)
__global__ __launch_bounds__(1024) void k_topk(const unsigned long long* __restrict__ keys,
                                               const float* __restrict__ out9,
                                               float* __restrict__ jx, float* __restrict__ jy) {
  int b = blockIdx.x;
  __shared__ unsigned long long cand[4096];
  __shared__ int cnt;
  int t = threadIdx.x;
  if (t == 0) cnt = 0;
#pragma unroll
  for (int i = t; i < 4096; i += 1024) cand[i] = 0ull;
  __syncthreads();
  const unsigned long long* K = keys + (size_t)b * HW;
  for (int i = t; i < HW; i += 1024) {
    unsigned long long k = K[i];
    if ((k >> 32) != 0ull) {
      int pos = atomicAdd(&cnt, 1);
      if (pos < 4096) cand[pos] = k;
    }
  }
  __syncthreads();
  // bitonic sort, descending (keys distinct except zero-padding)
  for (int k = 2; k <= 4096; k <<= 1) {
    for (int j = k >> 1; j > 0; j >>= 1) {
#pragma unroll
      for (int idx = t; idx < 4096; idx += 1024) {
        int ixj = idx ^ j;
        if (ixj > idx) {
          unsigned long long a = cand[idx], c = cand[ixj];
          bool up = ((idx & k) == 0);
          if (up ? (a < c) : (a > c)) { cand[idx] = c; cand[ixj] = a; }
        }
      }
      __syncthreads();
    }
  }
  if (t < NTOPK) {
    const float* o7 = out9 + (size_t)b * 9 * HW + 7 * HW;
    const float* o8 = out9 + (size_t)b * 9 * HW + 8 * HW;
    unsigned long long bb = cand[t];
    unsigned int vb = (unsigned int)(bb >> 32);
    float val = __uint_as_float(vb);
    if (vb != 0u && val > JUNC_TH) {
      int p = (int)(~((unsigned int)(bb & 0xffffffffull))) & (HW - 1);
      float ox = sigm(o7[p]) - 0.5f;
      float oy = sigm(o8[p]) - 0.5f;
      jx[b * NTOPK + t] = (float)(p & 127) + ox + 0.5f;
      jy[b * NTOPK + t] = (float)(p >> 7) + oy + 0.5f;
    } else {
      jx[b * NTOPK + t] = 1000000.0f;
      jy[b * NTOPK + t] = 1000000.0f;
    }
  }
}

// ---------------------------------------------------------------- per-line argmin assignment + lines2 output
__global__ __launch_bounds__(256) void k_lines(const float* __restrict__ lp,
                                               const float* __restrict__ jx,
                                               const float* __restrict__ jy,
                                               float4* __restrict__ lines4,
                                               int* __restrict__ iskeep,
                                               float* __restrict__ out_lines) {
  int b = blockIdx.y;
  int l = blockIdx.x * 256 + threadIdx.x;
  __shared__ float jxs[NTOPK], jys[NTOPK];
  for (int i = threadIdx.x; i < NTOPK; i += 256) {
    jxs[i] = jx[b * NTOPK + i];
    jys[i] = jy[b * NTOPK + i];
  }
  __syncthreads();
  int gl = b * HW + l;
  const float* L = lp + (size_t)gl * 4;
  float x1 = L[0], y1 = L[1], x2 = L[2], y2 = L[3];
  float bd1 = 3.4e38f, bd2 = 3.4e38f;
  int i1 = 0, i2 = 0;
  for (int j = 0; j < NTOPK; ++j) {
    float ax = __fsub_rn(x1, jxs[j]);
    float ay = __fsub_rn(y1, jys[j]);
    float d1 = __fadd_rn(__fmul_rn(ax, ax), __fmul_rn(ay, ay));
    if (d1 < bd1) { bd1 = d1; i1 = j; }
    float ex = __fsub_rn(x2, jxs[j]);
    float ey = __fsub_rn(y2, jys[j]);
    float d2 = __fadd_rn(__fmul_rn(ex, ex), __fmul_rn(ey, ey));
    if (d2 < bd2) { bd2 = d2; i2 = j; }
  }
  int imin = min(i1, i2), imax = max(i1, i2);
  float sx1 = jxs[imin], sy1 = jys[imin], sx2 = jxs[imax], sy2 = jys[imax];
  lines4[gl] = make_float4(sx1, sy1, sx2, sy2);
  iskeep[gl] = (imin < imax) ? 1 : 0;
  ((float4*)out_lines)[gl] = make_float4(sx1 * 4.0f, sy1 * 4.0f, sx2 * 4.0f, sy2 * 4.0f);
}

// ---------------------------------------------------------------- bilinear sample + maxpool
__global__ __launch_bounds__(128) void k_sample(const unsigned short* __restrict__ loi,
                                                const float4* __restrict__ lines4,
                                                unsigned short* __restrict__ xvec,
                                                int b_base, int l0, int rows_per_b) {
  __shared__ int   soff[2][32][4];
  __shared__ float swt[2][32][4];
  int b = b_base + blockIdx.y;
  int t = threadIdx.x;
  if (t < 64) {
    int li = t >> 5, k = t & 31;
    int l = l0 + blockIdx.x * 2 + li;
    float4 ln = lines4[b * HW + l];
    float tt = (float)k * (1.0f / 31.0f);
    float tc = 1.0f - tt;
    float px = ln.x * tt + ln.z * tc - 0.5f;
    float py = ln.y * tt + ln.w * tc - 0.5f;
    float px0 = fminf(fmaxf(floorf(px), 0.0f), 127.0f);
    float py0 = fminf(fmaxf(floorf(py), 0.0f), 127.0f);
    float px1 = fminf(px0 + 1.0f, 127.0f);
    float py1 = fminf(py0 + 1.0f, 127.0f);
    int ix0 = (int)px0, iy0 = (int)py0, ix1 = (int)px1, iy1 = (int)py1;
    float wy1 = __fsub_rn(py1, py), wy0 = __fsub_rn(py, py0);
    float wx1 = __fsub_rn(px1, px), wx0 = __fsub_rn(px, px0);
    soff[li][k][0] = (iy0 * WIDTH + ix0) * 128;
    soff[li][k][1] = (iy1 * WIDTH + ix0) * 128;
    soff[li][k][2] = (iy0 * WIDTH + ix1) * 128;
    soff[li][k][3] = (iy1 * WIDTH + ix1) * 128;
    swt[li][k][0] = __fmul_rn(wy1, wx1);   // wa -> r00
    swt[li][k][1] = __fmul_rn(wy0, wx1);   // wb -> r10
    swt[li][k][2] = __fmul_rn(wy1, wx0);   // wc -> r01
    swt[li][k][3] = __fmul_rn(wy0, wx0);   // wd -> r11
  }
  __syncthreads();
  int li = t >> 6, c2 = t & 63;            // channels 2*c2, 2*c2+1
  int l = l0 + blockIdx.x * 2 + li;
  const unsigned short* Lb = loi + (size_t)b * HW * 128 + (c2 << 1);
  float rm0 = -3.4e38f, rm1 = -3.4e38f;
  alignas(16) unsigned short outv[16];
#pragma unroll 4
  for (int k = 0; k < 32; ++k) {
    int4   o = *(const int4*)soff[li][k];
    float4 w = *(const float4*)swt[li][k];
    unsigned int u0 = *(const unsigned int*)(Lb + o.x);
    unsigned int u1 = *(const unsigned int*)(Lb + o.y);
    unsigned int u2 = *(const unsigned int*)(Lb + o.z);
    unsigned int u3 = *(const unsigned int*)(Lb + o.w);
    float2 v0 = bf2x2(u0), v1 = bf2x2(u1), v2 = bf2x2(u2), v3 = bf2x2(u3);
    float a0 = __fadd_rn(__fadd_rn(__fadd_rn(__fmul_rn(v0.x, w.x), __fmul_rn(v1.x, w.y)),
                                   __fmul_rn(v2.x, w.z)), __fmul_rn(v3.x, w.w));
    float a1 = __fadd_rn(__fadd_rn(__fadd_rn(__fmul_rn(v0.y, w.x), __fmul_rn(v1.y, w.y)),
                                   __fmul_rn(v2.y, w.z)), __fmul_rn(v3.y, w.w));
    rm0 = fmaxf(rm0, a0);
    rm1 = fmaxf(rm1, a1);
    if ((k & 3) == 3) {
      outv[k >> 2]       = f2bf(rm0);
      outv[8 + (k >> 2)] = f2bf(rm1);
      rm0 = -3.4e38f; rm1 = -3.4e38f;
    }
  }
  size_t xrow = (size_t)blockIdx.y * rows_per_b + (l - l0);
  unsigned short* dst = xvec + xrow * 1024 + c2 * 16;
  *(s16x8*)dst       = *(const s16x8*)outv;
  *(s16x8*)(dst + 8) = *(const s16x8*)(outv + 8);
}

// ---------------------------------------------------------------- shared FC K-loop: BM=128, BN=128, BK=32, 256 threads / 4 waves.
// A staged via global_load_lds (dbuf, 8 KB/iter). B loaded DIRECT global->VGPR
// (register prefetch distance 1, no LDS, no extra barrier dependency).
// LDS pipe per block-iter: 16 ds_read_b128 + 8 KB write (~256 cyc vs 960 in R6).
__device__ __forceinline__ void fc_kloop(const unsigned short* __restrict__ A,
                                         const unsigned short* __restrict__ Bt,
                                         short* sm, int m0, int n0,
                                         f32x4 acc[4][4]) {
  const int K = 1024;
  int t = threadIdx.x, lane = t & 63, w = t >> 6;   // w 0..3
  int wm = w & 1, wn = w >> 1;
  int lr = lane & 15, ls = lane >> 4;

  const unsigned short* gA0 = A + (size_t)(m0 + w * 16 + lr) * K + ls * 8;
  const unsigned short* gA1 = A + (size_t)(m0 + (w + 4) * 16 + lr) * K + ls * 8;
  int oA0 = w * 512 + lane * 8;
  int oA1 = (w + 4) * 512 + lane * 8;

  const unsigned short* gB0 = Bt + (size_t)(n0 + wn * 64 + lr) * K + ls * 8;
  const unsigned short* gB1 = gB0 + (size_t)16 * K;
  const unsigned short* gB2 = gB0 + (size_t)32 * K;
  const unsigned short* gB3 = gB0 + (size_t)48 * K;

  // prologue: stage A(0), load B(0)
  GLOAD_LDS16(gA0, sm + oA0);
  GLOAD_LDS16(gA1, sm + oA1);
  s16x8 bcur0 = *(const s16x8*)gB0;
  s16x8 bcur1 = *(const s16x8*)gB1;
  s16x8 bcur2 = *(const s16x8*)gB2;
  s16x8 bcur3 = *(const s16x8*)gB3;
  __syncthreads();

  int cur = 0;
  for (int k = 0; k < 32; ++k) {
    int nxt = cur ^ 1;
    int ko = ((k + 1) & 31) * 32;          // wrap at tail (junk prefetch, unused)
    short* d = sm + nxt * 4096;
    GLOAD_LDS16(gA0 + ko, d + oA0);
    GLOAD_LDS16(gA1 + ko, d + oA1);
    s16x8 bn0 = *(const s16x8*)(gB0 + ko);
    s16x8 bn1 = *(const s16x8*)(gB1 + ko);
    s16x8 bn2 = *(const s16x8*)(gB2 + ko);
    s16x8 bn3 = *(const s16x8*)(gB3 + ko);

    const short* As = sm + cur * 4096;
    s16x8 af[4];
#pragma unroll
    for (int mi = 0; mi < 4; ++mi) af[mi] = *(const s16x8*)(As + (wm * 4 + mi) * 512 + lane * 8);
#pragma unroll
    for (int mi = 0; mi < 4; ++mi) {
      acc[mi][0] = __builtin_amdgcn_mfma_f32_16x16x32_bf16(af[mi], bcur0, acc[mi][0], 0, 0, 0);
      acc[mi][1] = __builtin_amdgcn_mfma_f32_16x16x32_bf16(af[mi], bcur1, acc[mi][1], 0, 0, 0);
      acc[mi][2] = __builtin_amdgcn_mfma_f32_16x16x32_bf16(af[mi], bcur2, acc[mi][2], 0, 0, 0);
      acc[mi][3] = __builtin_amdgcn_mfma_f32_16x16x32_bf16(af[mi], bcur3, acc[mi][3], 0, 0, 0);
    }
    __syncthreads();
    cur = nxt;
    bcur0 = bn0; bcur1 = bn1; bcur2 = bn2; bcur3 = bn3;
  }
}

// ---------------------------------------------------------------- fc1: C = relu(A @ Bt^T + bias), bf16 out, 128x128 tile
__global__ __launch_bounds__(256) void k_fc1(const unsigned short* __restrict__ A,
                                             const unsigned short* __restrict__ Bt,
                                             const float* __restrict__ bias,
                                             unsigned short* __restrict__ C,
                                             int nm) {
  const int N = 1024;
  __shared__ __align__(16) short sm[17408];   // loop: 2x4096; epilogue: 128x136
  int t = threadIdx.x, lane = t & 63, w = t >> 6;
  int wm = w & 1, wn = w >> 1;
  int lr = lane & 15, ls = lane >> 4;
  int m_idx, n_idx;
  fc_tile_map(blockIdx.x, nm, m_idx, n_idx);
  int m0 = m_idx * 128, n0 = n_idx * 128;

  f32x4 acc[4][4];
#pragma unroll
  for (int i = 0; i < 4; ++i)
#pragma unroll
    for (int j = 0; j < 4; ++j) acc[i][j] = (f32x4){0.f, 0.f, 0.f, 0.f};

  fc_kloop(A, Bt, sm, m0, n0, acc);
  __syncthreads();

  // epilogue: stage C tile in LDS (stride 136 shorts), then coalesced stores
#pragma unroll
  for (int ni = 0; ni < 4; ++ni) {
    int cl = wn * 64 + ni * 16 + lr;
    float bv = bias[n0 + cl];
#pragma unroll
    for (int mi = 0; mi < 4; ++mi) {
      int rl = wm * 64 + mi * 16 + ls * 4;
#pragma unroll
      for (int r = 0; r < 4; ++r)
        sm[(rl + r) * 136 + cl] = (short)f2bf(fmaxf(acc[mi][ni][r] + bv, 0.0f));
    }
  }
  __syncthreads();
  {
    int row = t >> 1, half = t & 1;
    const short* src = sm + row * 136 + half * 64;
    unsigned short* dst = C + (size_t)(m0 + row) * N + n0 + half * 64;
#pragma unroll
    for (int i = 0; i < 8; ++i)
      *(s16x8*)(dst + i * 8) = *(const s16x8*)(src + i * 8);
  }
}

// ---------------------------------------------------------------- fc2 fused with logits: per-n0 partial sums (no atomics)
__global__ __launch_bounds__(256) void k_fc2log(const unsigned short* __restrict__ A,
                                                const unsigned short* __restrict__ Bt,
                                                const float* __restrict__ bias,
                                                const float* __restrict__ w3,
                                                float* __restrict__ logp,
                                                int base, int nm) {
  __shared__ __align__(16) short sm[8192];
  int t = threadIdx.x, lane = t & 63, w = t >> 6;
  int wm = w & 1, wn = w >> 1;
  int lr = lane & 15, ls = lane >> 4;
  int m_idx, n_idx;
  fc_tile_map(blockIdx.x, nm, m_idx, n_idx);
  int m0 = m_idx * 128, n0 = n_idx * 128;

  f32x4 acc[4][4];
#pragma unroll
  for (int i = 0; i < 4; ++i)
#pragma unroll
    for (int j = 0; j < 4; ++j) acc[i][j] = (f32x4){0.f, 0.f, 0.f, 0.f};

  fc_kloop(A, Bt, sm, m0, n0, acc);

  // epilogue: psum[mi][r] = sum over this wave's 64 cols of relu(acc+b2)*w3
  float psum[4][4];
#pragma unroll
  for (int mi = 0; mi < 4; ++mi)
#pragma unroll
    for (int r = 0; r < 4; ++r) psum[mi][r] = 0.0f;
#pragma unroll
  for (int ni = 0; ni < 4; ++ni) {
    int col = n0 + wn * 64 + ni * 16 + lr;
    float bv = bias[col];
    float wv = w3[col];
#pragma unroll
    for (int mi = 0; mi < 4; ++mi)
#pragma unroll
      for (int r = 0; r < 4; ++r)
        psum[mi][r] += fmaxf(acc[mi][ni][r] + bv, 0.0f) * wv;
  }
  // the two wn waves covering the same rows sum via LDS
  __syncthreads();
  float* red = (float*)sm;    // 128 rows x 2 floats
#pragma unroll
  for (int mi = 0; mi < 4; ++mi)
#pragma unroll
    for (int r = 0; r < 4; ++r) {
      float v = psum[mi][r];
      v += __shfl_xor(v, 1, 64);
      v += __shfl_xor(v, 2, 64);
      v += __shfl_xor(v, 4, 64);
      v += __shfl_xor(v, 8, 64);
      if (lr == 0) {
        int row = wm * 64 + mi * 16 + ls * 4 + r;
        red[row * 2 + wn] = v;
      }
    }
  __syncthreads();
  if (t < 128)
    logp[(size_t)(base + m0 + t) * 8 + n_idx] = red[t * 2] + red[t * 2 + 1];
}

// ---------------------------------------------------------------- final: reduce partials + sigmoid + keep
__global__ __launch_bounds__(256) void k_fin(const float* __restrict__ logp,
                                             const float* __restrict__ b3,
                                             const int* __restrict__ iskeep,
                                             float* __restrict__ oscore,
                                             float* __restrict__ okeep,
                                             int base) {
  int gl = base + blockIdx.x * 256 + threadIdx.x;
  const float4* p4 = (const float4*)(logp + (size_t)gl * 8);
  float4 a = p4[0], b = p4[1];
  float s = ((a.x + a.y) + (a.z + a.w)) + ((b.x + b.y) + (b.z + b.w));
  float sc = sigm(s + b3[0]);
  oscore[gl] = sc;
  okeep[gl] = (iskeep[gl] && sc > 0.05f) ? 1.0f : 0.0f;
}

// ================================================================ host
extern "C" void kernel_launch(void* const* d_in, const int* in_sizes, int n_in,
                              void* d_out, int out_size, void* d_ws, size_t ws_size,
                              hipStream_t stream) {
  const float* output     = (const float*)d_in[0];
  const float* features   = (const float*)d_in[1];
  const float* line_preds = (const float*)d_in[2];
  const float* conv_w     = (const float*)d_in[3];
  const float* conv_b     = (const float*)d_in[4];
  const float* w1         = (const float*)d_in[5];
  const float* b1         = (const float*)d_in[6];
  const float* w2         = (const float*)d_in[7];
  const float* b2         = (const float*)d_in[8];
  const float* w3         = (const float*)d_in[9];
  const float* b3         = (const float*)d_in[10];

  char* ws = (char*)d_ws;
  size_t off = 0;
  auto alloc = [&](size_t bytes) -> void* {
    void* p = ws + off;
    off += (bytes + 255) & ~(size_t)255;
    return p;
  };
  float* wt      = (float*)alloc((size_t)256 * 128 * 4);
  unsigned short* loi = (unsigned short*)alloc((size_t)NB * HW * 128 * 2);
  float* jloc    = (float*)alloc((size_t)NB * HW * 4);
  unsigned long long* keys = (unsigned long long*)alloc((size_t)NB * HW * 8);
  float* jx      = (float*)alloc((size_t)NB * NTOPK * 4);
  float* jy      = (float*)alloc((size_t)NB * NTOPK * 4);
  float4* lines4 = (float4*)alloc((size_t)NB * HW * 16);
  int* iskeep    = (int*)alloc((size_t)NB * HW * 4);
  float* logp    = (float*)alloc((size_t)NB * HW * 8 * 4);   // 8 partials per line
  unsigned short* w1b = (unsigned short*)alloc((size_t)1024 * 1024 * 2);   // [N][K] bf16
  unsigned short* w2b = (unsigned short*)alloc((size_t)1024 * 1024 * 2);
  size_t fixed = off;

  // pick activation size: merged (both images, M=32768) if it fits, else per-image chunks
  bool merged = (fixed + (size_t)2 * NB * HW * 1024 * 2 + 512 <= ws_size);
  int CH = 256;
  if (!merged) {
    const int cands[7] = {16384, 8192, 4096, 2048, 1024, 512, 256};
    for (int ci = 0; ci < 7; ++ci) {
      if (fixed + (size_t)2 * cands[ci] * 1024 * 2 + 512 <= ws_size) { CH = cands[ci]; break; }
    }
  }
  size_t actrows = merged ? (size_t)NB * HW : (size_t)CH;
  unsigned short* xvec = (unsigned short*)alloc(actrows * 1024 * 2);
  unsigned short* h1   = (unsigned short*)alloc(actrows * 1024 * 2);

  float* out_lines  = (float*)d_out;              // (B, L, 2, 2)
  float* out_scores = out_lines + (size_t)NB * HW * 4;
  float* out_keep   = out_scores + (size_t)NB * HW;

  k_transpose_w<<<128, 256, 0, stream>>>(conv_w, wt);
  k_wtrans<<<dim3(32, 32), 256, 0, stream>>>(w1, w1b);
  k_wtrans<<<dim3(32, 32), 256, 0, stream>>>(w2, w2b);
  k_loi<<<dim3(HW / 64, NB), 256, 0, stream>>>(features, wt, conv_b, loi);
  k_jloc<<<NB * HW / 256, 256, 0, stream>>>(output, jloc);
  k_nmskey<<<NB * HW / 256, 256, 0, stream>>>(jloc, keys);
  k_topk<<<NB, 1024, 0, stream>>>(keys, output, jx, jy);
  k_lines<<<dim3(HW / 256, NB), 256, 0, stream>>>(line_preds, jx, jy, lines4, iskeep, out_lines);

  if (merged) {
    int M = NB * HW, nm = M / 128;
    k_sample<<<dim3(HW / 2, NB), 128, 0, stream>>>(loi, lines4, xvec, 0, 0, HW);
    k_fc1<<<nm * 8, 256, 0, stream>>>(xvec, w1b, b1, h1, nm);
    k_fc2log<<<nm * 8, 256, 0, stream>>>(h1, w2b, b2, w3, logp, 0, nm);
    k_fin<<<M / 256, 256, 0, stream>>>(logp, b3, iskeep, out_scores, out_keep, 0);
  } else {
    int nchunk = HW / CH, nm = CH / 128;
    for (int b = 0; b < NB; ++b) {
      for (int ci = 0; ci < nchunk; ++ci) {
        int l0 = ci * CH;
        int base = b * HW + l0;
        k_sample<<<dim3(CH / 2, 1), 128, 0, stream>>>(loi, lines4, xvec, b, l0, CH);
        k_fc1<<<nm * 8, 256, 0, stream>>>(xvec, w1b, b1, h1, nm);
        k_fc2log<<<nm * 8, 256, 0, stream>>>(h1, w2b, b2, w3, logp, base, nm);
        k_fin<<<CH / 256, 256, 0, stream>>>(logp, b3, iskeep, out_scores, out_keep, base);
      }
    }
  }
}

// Round 9
// 470.784 us; speedup vs baseline: 1.3951x; 1.3951x over previous
//
#include <hip/hip_runtime.h>
#include <hip/hip_bf16.h>
#include <cstdint>
#include <cstddef>

#define HW     16384      // H*W
#define WIDTH  128
#define NB     2
#define NTOPK  300
#define JUNC_TH 0.008f

typedef __attribute__((ext_vector_type(8))) short s16x8;
typedef __attribute__((ext_vector_type(4))) float f32x4;

// ---------------------------------------------------------------- utilities
__device__ __forceinline__ float sigm(float x) { return 1.0f / (1.0f + expf(-x)); }

__device__ __forceinline__ unsigned short f2bf(float f) {
  __hip_bfloat16 h = __float2bfloat16(f);
  return __hip_bfloat16_raw(h).x;
}
__device__ __forceinline__ float bf2f(unsigned short u) {
  __hip_bfloat16_raw r; r.x = u;
  return __bfloat162float(__hip_bfloat16(r));
}
__device__ __forceinline__ float2 bf2x2(unsigned int u) {
  return make_float2(__uint_as_float(u << 16), __uint_as_float(u & 0xffff0000u));
}

#define GLOAD_LDS16(gp, lp)                                                        \
  __builtin_amdgcn_global_load_lds((const __attribute__((address_space(1))) void*)(gp), \
                                   (__attribute__((address_space(3))) void*)(lp), 16, 0, 0)

// ---------------------------------------------------------------- W transpose (256x128 <- 128x256), fp32
__global__ void k_transpose_w(const float* __restrict__ w, float* __restrict__ wt) {
  int i = blockIdx.x * 256 + threadIdx.x;   // 32768
  int d = i & 127, c = i >> 7;
  wt[c * 128 + d] = w[d * 256 + c];
}

// ---------------------------------------------------------------- FC weight transpose+cast: wt_bf16[n][k] = w[k][n]
__global__ __launch_bounds__(256) void k_wtrans(const float* __restrict__ w,
                                                unsigned short* __restrict__ wt) {
  __shared__ float tile[32][33];
  int n0 = blockIdx.x * 32, k0 = blockIdx.y * 32;
  int tx = threadIdx.x & 31, ty = threadIdx.x >> 5;   // 32 x 8
#pragma unroll
  for (int r = 0; r < 32; r += 8)
    tile[ty + r][tx] = w[(size_t)(k0 + ty + r) * 1024 + n0 + tx];
  __syncthreads();
#pragma unroll
  for (int r = 0; r < 32; r += 8)
    wt[(size_t)(n0 + ty + r) * 1024 + k0 + tx] = f2bf(tile[tx][ty + r]);
}

// ---------------------------------------------------------------- loi GEMM (fp32 math, bf16 store): loi_t[b][p][d]
__global__ __launch_bounds__(256) void k_loi(const float* __restrict__ F,
                                             const float* __restrict__ wt,
                                             const float* __restrict__ bias,
                                             unsigned short* __restrict__ loi) {
  int b = blockIdx.y;
  int p0 = blockIdx.x * 64;
  __shared__ float As[8][64];
  __shared__ float Bs[8][128];
  int t = threadIdx.x;
  int tn = t & 15;    // n group: n = tn*8
  int tm = t >> 4;    // m group: m = tm*4
  float acc[4][8];
#pragma unroll
  for (int i = 0; i < 4; ++i)
#pragma unroll
    for (int j = 0; j < 8; ++j) acc[i][j] = 0.0f;

  const float* Fb = F + (size_t)b * 256 * HW;
  for (int c0 = 0; c0 < 256; c0 += 8) {
    __syncthreads();
    if (t < 128) {
      int kk = t >> 4, mv = t & 15;
      float4 v = *(const float4*)(Fb + (size_t)(c0 + kk) * HW + p0 + mv * 4);
      *(float4*)&As[kk][mv * 4] = v;
    }
    {
      int kk = t >> 5, dv = t & 31;
      float4 v = *(const float4*)(wt + (size_t)(c0 + kk) * 128 + dv * 4);
      *(float4*)&Bs[kk][dv * 4] = v;
    }
    __syncthreads();
#pragma unroll
    for (int kk = 0; kk < 8; ++kk) {
      float4 a4 = *(const float4*)&As[kk][tm * 4];
      float4 b0 = *(const float4*)&Bs[kk][tn * 8];
      float4 b1 = *(const float4*)&Bs[kk][tn * 8 + 4];
      float av[4] = {a4.x, a4.y, a4.z, a4.w};
      float bv[8] = {b0.x, b0.y, b0.z, b0.w, b1.x, b1.y, b1.z, b1.w};
#pragma unroll
      for (int i = 0; i < 4; ++i)
#pragma unroll
        for (int j = 0; j < 8; ++j) acc[i][j] += av[i] * bv[j];
    }
  }
  float4 c0v = *(const float4*)(bias + tn * 8);
  float4 c1v = *(const float4*)(bias + tn * 8 + 4);
  float bb[8] = {c0v.x, c0v.y, c0v.z, c0v.w, c1v.x, c1v.y, c1v.z, c1v.w};
#pragma unroll
  for (int i = 0; i < 4; ++i) {
    int p = p0 + tm * 4 + i;
    alignas(16) unsigned short o[8];
#pragma unroll
    for (int j = 0; j < 8; ++j) o[j] = f2bf(acc[i][j] + bb[j]);
    *(s16x8*)(loi + ((size_t)b * HW + p) * 128 + tn * 8) = *(const s16x8*)o;
  }
}

// ---------------------------------------------------------------- jloc = softmax(out9[5:7])[1]
__global__ void k_jloc(const float* __restrict__ out9, float* __restrict__ jloc) {
  int i = blockIdx.x * 256 + threadIdx.x;    // NB*HW
  int b = i >> 14, p = i & (HW - 1);
  const float* base = out9 + (size_t)b * 9 * HW;
  float o5 = base[5 * HW + p], o6 = base[6 * HW + p];
  float m = fmaxf(o5, o6);
  float e5 = expf(o5 - m), e6 = expf(o6 - m);
  jloc[i] = e6 / (e5 + e6);
}

// ---------------------------------------------------------------- NMS + sortable key
__global__ void k_nmskey(const float* __restrict__ jloc, unsigned long long* __restrict__ keys) {
  int i = blockIdx.x * 256 + threadIdx.x;
  int b = i >> 14, p = i & (HW - 1);
  int y = p >> 7, x = p & 127;
  const float* J = jloc + (size_t)b * HW;
  float c = J[p];
  float m = c;
  for (int dy = -1; dy <= 1; ++dy) {
    int yy = y + dy;
    if (yy < 0 || yy > 127) continue;
    for (int dx = -1; dx <= 1; ++dx) {
      int xx = x + dx;
      if (xx < 0 || xx > 127) continue;
      m = fmaxf(m, J[yy * WIDTH + xx]);
    }
  }
  unsigned int vb = (c == m) ? __float_as_uint(c) : 0u;   // jloc > 0 always -> bits monotone
  keys[i] = ((unsigned long long)vb << 32) | (unsigned int)(~p);
}

// ---------------------------------------------------------------- top-300 per image via bitonic sort (1 block/image)
__global__ __launch_bounds__(1024) void k_topk(const unsigned long long* __restrict__ keys,
                                               const float* __restrict__ out9,
                                               float* __restrict__ jx, float* __restrict__ jy) {
  int b = blockIdx.x;
  __shared__ unsigned long long cand[4096];
  __shared__ int cnt;
  int t = threadIdx.x;
  if (t == 0) cnt = 0;
#pragma unroll
  for (int i = t; i < 4096; i += 1024) cand[i] = 0ull;
  __syncthreads();
  const unsigned long long* K = keys + (size_t)b * HW;
  for (int i = t; i < HW; i += 1024) {
    unsigned long long k = K[i];
    if ((k >> 32) != 0ull) {
      int pos = atomicAdd(&cnt, 1);
      if (pos < 4096) cand[pos] = k;
    }
  }
  __syncthreads();
  // bitonic sort, descending (keys distinct except zero-padding)
  for (int k = 2; k <= 4096; k <<= 1) {
    for (int j = k >> 1; j > 0; j >>= 1) {
#pragma unroll
      for (int idx = t; idx < 4096; idx += 1024) {
        int ixj = idx ^ j;
        if (ixj > idx) {
          unsigned long long a = cand[idx], c = cand[ixj];
          bool up = ((idx & k) == 0);
          if (up ? (a < c) : (a > c)) { cand[idx] = c; cand[ixj] = a; }
        }
      }
      __syncthreads();
    }
  }
  if (t < NTOPK) {
    const float* o7 = out9 + (size_t)b * 9 * HW + 7 * HW;
    const float* o8 = out9 + (size_t)b * 9 * HW + 8 * HW;
    unsigned long long bb = cand[t];
    unsigned int vb = (unsigned int)(bb >> 32);
    float val = __uint_as_float(vb);
    if (vb != 0u && val > JUNC_TH) {
      int p = (int)(~((unsigned int)(bb & 0xffffffffull))) & (HW - 1);
      float ox = sigm(o7[p]) - 0.5f;
      float oy = sigm(o8[p]) - 0.5f;
      jx[b * NTOPK + t] = (float)(p & 127) + ox + 0.5f;
      jy[b * NTOPK + t] = (float)(p >> 7) + oy + 0.5f;
    } else {
      jx[b * NTOPK + t] = 1000000.0f;
      jy[b * NTOPK + t] = 1000000.0f;
    }
  }
}

// ---------------------------------------------------------------- per-line argmin assignment + lines2 output
__global__ __launch_bounds__(256) void k_lines(const float* __restrict__ lp,
                                               const float* __restrict__ jx,
                                               const float* __restrict__ jy,
                                               float4* __restrict__ lines4,
                                               int* __restrict__ iskeep,
                                               float* __restrict__ out_lines) {
  int b = blockIdx.y;
  int l = blockIdx.x * 256 + threadIdx.x;
  __shared__ float jxs[NTOPK], jys[NTOPK];
  for (int i = threadIdx.x; i < NTOPK; i += 256) {
    jxs[i] = jx[b * NTOPK + i];
    jys[i] = jy[b * NTOPK + i];
  }
  __syncthreads();
  int gl = b * HW + l;
  const float* L = lp + (size_t)gl * 4;
  float x1 = L[0], y1 = L[1], x2 = L[2], y2 = L[3];
  float bd1 = 3.4e38f, bd2 = 3.4e38f;
  int i1 = 0, i2 = 0;
  for (int j = 0; j < NTOPK; ++j) {
    float ax = __fsub_rn(x1, jxs[j]);
    float ay = __fsub_rn(y1, jys[j]);
    float d1 = __fadd_rn(__fmul_rn(ax, ax), __fmul_rn(ay, ay));
    if (d1 < bd1) { bd1 = d1; i1 = j; }
    float ex = __fsub_rn(x2, jxs[j]);
    float ey = __fsub_rn(y2, jys[j]);
    float d2 = __fadd_rn(__fmul_rn(ex, ex), __fmul_rn(ey, ey));
    if (d2 < bd2) { bd2 = d2; i2 = j; }
  }
  int imin = min(i1, i2), imax = max(i1, i2);
  float sx1 = jxs[imin], sy1 = jys[imin], sx2 = jxs[imax], sy2 = jys[imax];
  lines4[gl] = make_float4(sx1, sy1, sx2, sy2);
  iskeep[gl] = (imin < imax) ? 1 : 0;
  ((float4*)out_lines)[gl] = make_float4(sx1 * 4.0f, sy1 * 4.0f, sx2 * 4.0f, sy2 * 4.0f);
}

// ---------------------------------------------------------------- bilinear sample + maxpool
__global__ __launch_bounds__(128) void k_sample(const unsigned short* __restrict__ loi,
                                                const float4* __restrict__ lines4,
                                                unsigned short* __restrict__ xvec,
                                                int b_base, int l0, int rows_per_b) {
  __shared__ int   soff[2][32][4];
  __shared__ float swt[2][32][4];
  int b = b_base + blockIdx.y;
  int t = threadIdx.x;
  if (t < 64) {
    int li = t >> 5, k = t & 31;
    int l = l0 + blockIdx.x * 2 + li;
    float4 ln = lines4[b * HW + l];
    float tt = (float)k * (1.0f / 31.0f);
    float tc = 1.0f - tt;
    float px = ln.x * tt + ln.z * tc - 0.5f;
    float py = ln.y * tt + ln.w * tc - 0.5f;
    float px0 = fminf(fmaxf(floorf(px), 0.0f), 127.0f);
    float py0 = fminf(fmaxf(floorf(py), 0.0f), 127.0f);
    float px1 = fminf(px0 + 1.0f, 127.0f);
    float py1 = fminf(py0 + 1.0f, 127.0f);
    int ix0 = (int)px0, iy0 = (int)py0, ix1 = (int)px1, iy1 = (int)py1;
    float wy1 = __fsub_rn(py1, py), wy0 = __fsub_rn(py, py0);
    float wx1 = __fsub_rn(px1, px), wx0 = __fsub_rn(px, px0);
    soff[li][k][0] = (iy0 * WIDTH + ix0) * 128;
    soff[li][k][1] = (iy1 * WIDTH + ix0) * 128;
    soff[li][k][2] = (iy0 * WIDTH + ix1) * 128;
    soff[li][k][3] = (iy1 * WIDTH + ix1) * 128;
    swt[li][k][0] = __fmul_rn(wy1, wx1);   // wa -> r00
    swt[li][k][1] = __fmul_rn(wy0, wx1);   // wb -> r10
    swt[li][k][2] = __fmul_rn(wy1, wx0);   // wc -> r01
    swt[li][k][3] = __fmul_rn(wy0, wx0);   // wd -> r11
  }
  __syncthreads();
  int li = t >> 6, c2 = t & 63;            // channels 2*c2, 2*c2+1
  int l = l0 + blockIdx.x * 2 + li;
  const unsigned short* Lb = loi + (size_t)b * HW * 128 + (c2 << 1);
  float rm0 = -3.4e38f, rm1 = -3.4e38f;
  alignas(16) unsigned short outv[16];
#pragma unroll 4
  for (int k = 0; k < 32; ++k) {
    int4   o = *(const int4*)soff[li][k];
    float4 w = *(const float4*)swt[li][k];
    unsigned int u0 = *(const unsigned int*)(Lb + o.x);
    unsigned int u1 = *(const unsigned int*)(Lb + o.y);
    unsigned int u2 = *(const unsigned int*)(Lb + o.z);
    unsigned int u3 = *(const unsigned int*)(Lb + o.w);
    float2 v0 = bf2x2(u0), v1 = bf2x2(u1), v2 = bf2x2(u2), v3 = bf2x2(u3);
    float a0 = __fadd_rn(__fadd_rn(__fadd_rn(__fmul_rn(v0.x, w.x), __fmul_rn(v1.x, w.y)),
                                   __fmul_rn(v2.x, w.z)), __fmul_rn(v3.x, w.w));
    float a1 = __fadd_rn(__fadd_rn(__fadd_rn(__fmul_rn(v0.y, w.x), __fmul_rn(v1.y, w.y)),
                                   __fmul_rn(v2.y, w.z)), __fmul_rn(v3.y, w.w));
    rm0 = fmaxf(rm0, a0);
    rm1 = fmaxf(rm1, a1);
    if ((k & 3) == 3) {
      outv[k >> 2]       = f2bf(rm0);
      outv[8 + (k >> 2)] = f2bf(rm1);
      rm0 = -3.4e38f; rm1 = -3.4e38f;
    }
  }
  size_t xrow = (size_t)blockIdx.y * rows_per_b + (l - l0);
  unsigned short* dst = xvec + xrow * 1024 + c2 * 16;
  *(s16x8*)dst       = *(const s16x8*)outv;
  *(s16x8*)(dst + 8) = *(const s16x8*)(outv + 8);
}

// ---------------------------------------------------------------- shared FC K-loop: BM=256, BN=256, BK=32, 512 threads / 8 waves.
// Wave w: wm=w&3 (64-row slice), wn=w>>2 (128-col slice). acc 4x8.
// Per LDS buffer: A 16 tiles x 512 shorts + B 16 tiles x 512 = 16384 shorts (32 KB).
// Double-buffered: 64 KB. global_load_lds staging (4 per wave per iter), 1 barrier/iter.
__device__ __forceinline__ void fc_kloop(const unsigned short* __restrict__ A,
                                         const unsigned short* __restrict__ Bt,
                                         short* sm, int m0, int n0,
                                         f32x4 acc[4][8]) {
  const int K = 1024;
  int t = threadIdx.x, lane = t & 63, w = t >> 6;   // w 0..7
  int wm = w & 3, wn = w >> 2;
  int lr = lane & 15, ls = lane >> 4;

  const unsigned short* gA0 = A + (size_t)(m0 + w * 16 + lr) * K + ls * 8;
  const unsigned short* gA1 = A + (size_t)(m0 + (w + 8) * 16 + lr) * K + ls * 8;
  const unsigned short* gB0 = Bt + (size_t)(n0 + w * 16 + lr) * K + ls * 8;
  const unsigned short* gB1 = Bt + (size_t)(n0 + (w + 8) * 16 + lr) * K + ls * 8;
  int oA0 = w * 512 + lane * 8;
  int oA1 = (w + 8) * 512 + lane * 8;
  int oB0 = 8192 + w * 512 + lane * 8;
  int oB1 = 8192 + (w + 8) * 512 + lane * 8;

  GLOAD_LDS16(gA0, sm + oA0);
  GLOAD_LDS16(gA1, sm + oA1);
  GLOAD_LDS16(gB0, sm + oB0);
  GLOAD_LDS16(gB1, sm + oB1);
  __syncthreads();

  int cur = 0;
  for (int k0 = 0; k0 < K; k0 += 32) {
    int nxt = cur ^ 1;
    if (k0 + 32 < K) {
      int ko = k0 + 32;
      short* d = sm + nxt * 16384;
      GLOAD_LDS16(gA0 + ko, d + oA0);
      GLOAD_LDS16(gA1 + ko, d + oA1);
      GLOAD_LDS16(gB0 + ko, d + oB0);
      GLOAD_LDS16(gB1 + ko, d + oB1);
    }
    const short* As = sm + cur * 16384;
    const short* Bs = As + 8192;
    s16x8 af[4];
#pragma unroll
    for (int mi = 0; mi < 4; ++mi) af[mi] = *(const s16x8*)(As + (wm * 4 + mi) * 512 + lane * 8);
#pragma unroll
    for (int ni = 0; ni < 8; ++ni) {
      s16x8 bf = *(const s16x8*)(Bs + (wn * 8 + ni) * 512 + lane * 8);
#pragma unroll
      for (int mi = 0; mi < 4; ++mi)
        acc[mi][ni] = __builtin_amdgcn_mfma_f32_16x16x32_bf16(af[mi], bf, acc[mi][ni], 0, 0, 0);
    }
    __syncthreads();
    cur = nxt;
  }
}

// ---------------------------------------------------------------- fc1: C = relu(A @ Bt^T + bias), bf16 out, 256x256 tile
__global__ __launch_bounds__(512, 2) void k_fc1(const unsigned short* __restrict__ A,
                                                const unsigned short* __restrict__ Bt,
                                                const float* __restrict__ bias,
                                                unsigned short* __restrict__ C) {
  const int N = 1024;
  __shared__ __align__(16) short sm[32768];   // 64 KB: dbuf loop; epilogue reuses 64x264
  int t = threadIdx.x, lane = t & 63, w = t >> 6;
  int wm = w & 3, wn = w >> 2;
  int lr = lane & 15, ls = lane >> 4;
  int m0 = (blockIdx.x >> 2) * 256, n0 = (blockIdx.x & 3) * 256;

  f32x4 acc[4][8];
#pragma unroll
  for (int i = 0; i < 4; ++i)
#pragma unroll
    for (int j = 0; j < 8; ++j) acc[i][j] = (f32x4){0.f, 0.f, 0.f, 0.f};

  fc_kloop(A, Bt, sm, m0, n0, acc);
  __syncthreads();

  // 4-pass LDS-staged epilogue: pass p stages rows [p*64, p*64+64) into 64x264
  for (int p = 0; p < 4; ++p) {
    if (wm == p) {
#pragma unroll
      for (int ni = 0; ni < 8; ++ni) {
        int cl = wn * 128 + ni * 16 + lr;
        float bv = bias[n0 + cl];
#pragma unroll
        for (int mi = 0; mi < 4; ++mi) {
          int rl = mi * 16 + ls * 4;
#pragma unroll
          for (int r = 0; r < 4; ++r)
            sm[(rl + r) * 264 + cl] = (short)f2bf(fmaxf(acc[mi][ni][r] + bv, 0.0f));
        }
      }
    }
    __syncthreads();
    {
      int row = t >> 3, seg = t & 7;   // 64 rows x 8 segs of 32 cols
      const short* src = sm + row * 264 + seg * 32;
      unsigned short* dst = C + (size_t)(m0 + p * 64 + row) * N + n0 + seg * 32;
      *(s16x8*)dst       = *(const s16x8*)src;
      *(s16x8*)(dst + 8) = *(const s16x8*)(src + 8);
      *(s16x8*)(dst + 16) = *(const s16x8*)(src + 16);
      *(s16x8*)(dst + 24) = *(const s16x8*)(src + 24);
    }
    __syncthreads();
  }
}

// ---------------------------------------------------------------- fc2 fused with logits: per-n0 partial sums (no atomics)
// logp[(base+row)*4 + n_idx] = sum over this block's 256 cols of relu(...)*w3
__global__ __launch_bounds__(512, 2) void k_fc2log(const unsigned short* __restrict__ A,
                                                   const unsigned short* __restrict__ Bt,
                                                   const float* __restrict__ bias,
                                                   const float* __restrict__ w3,
                                                   float* __restrict__ logp,
                                                   int base) {
  __shared__ __align__(16) short sm[32768];
  int t = threadIdx.x, lane = t & 63, w = t >> 6;
  int wm = w & 3, wn = w >> 2;
  int lr = lane & 15, ls = lane >> 4;
  int n_idx = blockIdx.x & 3;
  int m0 = (blockIdx.x >> 2) * 256, n0 = n_idx * 256;

  f32x4 acc[4][8];
#pragma unroll
  for (int i = 0; i < 4; ++i)
#pragma unroll
    for (int j = 0; j < 8; ++j) acc[i][j] = (f32x4){0.f, 0.f, 0.f, 0.f};

  fc_kloop(A, Bt, sm, m0, n0, acc);

  float psum[4][4];
#pragma unroll
  for (int mi = 0; mi < 4; ++mi)
#pragma unroll
    for (int r = 0; r < 4; ++r) psum[mi][r] = 0.0f;
#pragma unroll
  for (int ni = 0; ni < 8; ++ni) {
    int col = n0 + wn * 128 + ni * 16 + lr;
    float bv = bias[col];
    float wv = w3[col];
#pragma unroll
    for (int mi = 0; mi < 4; ++mi)
#pragma unroll
      for (int r = 0; r < 4; ++r)
        psum[mi][r] += fmaxf(acc[mi][ni][r] + bv, 0.0f) * wv;
  }
  __syncthreads();
  float* red = (float*)sm;    // 256 rows x 2 (wn halves)
#pragma unroll
  for (int mi = 0; mi < 4; ++mi)
#pragma unroll
    for (int r = 0; r < 4; ++r) {
      float v = psum[mi][r];
      v += __shfl_xor(v, 1, 64);
      v += __shfl_xor(v, 2, 64);
      v += __shfl_xor(v, 4, 64);
      v += __shfl_xor(v, 8, 64);
      if (lr == 0) {
        int row = wm * 64 + mi * 16 + ls * 4 + r;
        red[row * 2 + wn] = v;
      }
    }
  __syncthreads();
  if (t < 256)
    logp[(size_t)(base + m0 + t) * 4 + n_idx] = red[t * 2] + red[t * 2 + 1];
}

// ---------------------------------------------------------------- final: reduce partials + sigmoid + keep
__global__ __launch_bounds__(256) void k_fin(const float* __restrict__ logp,
                                             const float* __restrict__ b3,
                                             const int* __restrict__ iskeep,
                                             float* __restrict__ oscore,
                                             float* __restrict__ okeep,
                                             int base) {
  int gl = base + blockIdx.x * 256 + threadIdx.x;
  float4 a = ((const float4*)logp)[gl];
  float s = (a.x + a.y) + (a.z + a.w);
  float sc = sigm(s + b3[0]);
  oscore[gl] = sc;
  okeep[gl] = (iskeep[gl] && sc > 0.05f) ? 1.0f : 0.0f;
}

// ================================================================ host
extern "C" void kernel_launch(void* const* d_in, const int* in_sizes, int n_in,
                              void* d_out, int out_size, void* d_ws, size_t ws_size,
                              hipStream_t stream) {
  const float* output     = (const float*)d_in[0];
  const float* features   = (const float*)d_in[1];
  const float* line_preds = (const float*)d_in[2];
  const float* conv_w     = (const float*)d_in[3];
  const float* conv_b     = (const float*)d_in[4];
  const float* w1         = (const float*)d_in[5];
  const float* b1         = (const float*)d_in[6];
  const float* w2         = (const float*)d_in[7];
  const float* b2         = (const float*)d_in[8];
  const float* w3         = (const float*)d_in[9];
  const float* b3         = (const float*)d_in[10];

  char* ws = (char*)d_ws;
  size_t off = 0;
  auto alloc = [&](size_t bytes) -> void* {
    void* p = ws + off;
    off += (bytes + 255) & ~(size_t)255;
    return p;
  };
  float* wt      = (float*)alloc((size_t)256 * 128 * 4);
  unsigned short* loi = (unsigned short*)alloc((size_t)NB * HW * 128 * 2);
  float* jloc    = (float*)alloc((size_t)NB * HW * 4);
  unsigned long long* keys = (unsigned long long*)alloc((size_t)NB * HW * 8);
  float* jx      = (float*)alloc((size_t)NB * NTOPK * 4);
  float* jy      = (float*)alloc((size_t)NB * NTOPK * 4);
  float4* lines4 = (float4*)alloc((size_t)NB * HW * 16);
  int* iskeep    = (int*)alloc((size_t)NB * HW * 4);
  float* logp    = (float*)alloc((size_t)NB * HW * 4 * 4);   // 4 partials per line
  unsigned short* w1b = (unsigned short*)alloc((size_t)1024 * 1024 * 2);   // [N][K] bf16
  unsigned short* w2b = (unsigned short*)alloc((size_t)1024 * 1024 * 2);
  size_t fixed = off;

  // pick activation size: merged (both images, M=32768) if it fits, else per-image chunks
  bool merged = (fixed + (size_t)2 * NB * HW * 1024 * 2 + 512 <= ws_size);
  int CH = 256;
  if (!merged) {
    const int cands[7] = {16384, 8192, 4096, 2048, 1024, 512, 256};
    for (int ci = 0; ci < 7; ++ci) {
      if (fixed + (size_t)2 * cands[ci] * 1024 * 2 + 512 <= ws_size) { CH = cands[ci]; break; }
    }
  }
  size_t actrows = merged ? (size_t)NB * HW : (size_t)CH;
  unsigned short* xvec = (unsigned short*)alloc(actrows * 1024 * 2);
  unsigned short* h1   = (unsigned short*)alloc(actrows * 1024 * 2);

  float* out_lines  = (float*)d_out;              // (B, L, 2, 2)
  float* out_scores = out_lines + (size_t)NB * HW * 4;
  float* out_keep   = out_scores + (size_t)NB * HW;

  k_transpose_w<<<128, 256, 0, stream>>>(conv_w, wt);
  k_wtrans<<<dim3(32, 32), 256, 0, stream>>>(w1, w1b);
  k_wtrans<<<dim3(32, 32), 256, 0, stream>>>(w2, w2b);
  k_loi<<<dim3(HW / 64, NB), 256, 0, stream>>>(features, wt, conv_b, loi);
  k_jloc<<<NB * HW / 256, 256, 0, stream>>>(output, jloc);
  k_nmskey<<<NB * HW / 256, 256, 0, stream>>>(jloc, keys);
  k_topk<<<NB, 1024, 0, stream>>>(keys, output, jx, jy);
  k_lines<<<dim3(HW / 256, NB), 256, 0, stream>>>(line_preds, jx, jy, lines4, iskeep, out_lines);

  if (merged) {
    int M = NB * HW, nm = M / 256;
    k_sample<<<dim3(HW / 2, NB), 128, 0, stream>>>(loi, lines4, xvec, 0, 0, HW);
    k_fc1<<<nm * 4, 512, 0, stream>>>(xvec, w1b, b1, h1);
    k_fc2log<<<nm * 4, 512, 0, stream>>>(h1, w2b, b2, w3, logp, 0);
    k_fin<<<M / 256, 256, 0, stream>>>(logp, b3, iskeep, out_scores, out_keep, 0);
  } else {
    int nchunk = HW / CH, nm = CH / 256;
    for (int b = 0; b < NB; ++b) {
      for (int ci = 0; ci < nchunk; ++ci) {
        int l0 = ci * CH;
        int base = b * HW + l0;
        k_sample<<<dim3(CH / 2, 1), 128, 0, stream>>>(loi, lines4, xvec, b, l0, CH);
        k_fc1<<<nm * 4, 512, 0, stream>>>(xvec, w1b, b1, h1);
        k_fc2log<<<nm * 4, 512, 0, stream>>>(h1, w2b, b2, w3, logp, base);
        k_fin<<<CH / 256, 256, 0, stream>>>(logp, b3, iskeep, out_scores, out_keep, base);
      }
    }
  }
}

// Round 10
// 410.646 us; speedup vs baseline: 1.5994x; 1.1464x over previous
//
#include <hip/hip_runtime.h>
#include <hip/hip_bf16.h>
#include <cstdint>
#include <cstddef>

#define HW     16384      // H*W
#define WIDTH  128
#define NB     2
#define NTOPK  300
#define JUNC_TH 0.008f

typedef __attribute__((ext_vector_type(8))) short s16x8;
typedef __attribute__((ext_vector_type(4))) float f32x4;

// ---------------------------------------------------------------- utilities
__device__ __forceinline__ float sigm(float x) { return 1.0f / (1.0f + expf(-x)); }

__device__ __forceinline__ unsigned short f2bf(float f) {
  __hip_bfloat16 h = __float2bfloat16(f);
  return __hip_bfloat16_raw(h).x;
}
__device__ __forceinline__ float2 bf2x2(unsigned int u) {
  return make_float2(__uint_as_float(u << 16), __uint_as_float(u & 0xffff0000u));
}
// OCP e4m3 conversion via v_cvt_pk_fp8_f32 (gfx950 HW format is OCP)
__device__ __forceinline__ unsigned char f2fp8(float v) {
  return (unsigned char)(__builtin_amdgcn_cvt_pk_fp8_f32(v, 0.0f, 0, false) & 0xff);
}

#define GLOAD_LDS16(gp, lp)                                                        \
  __builtin_amdgcn_global_load_lds((const __attribute__((address_space(1))) void*)(gp), \
                                   (__attribute__((address_space(3))) void*)(lp), 16, 0, 0)

// XCD-cohort swizzle: consecutive blocks round-robin across 8 XCDs; give each
// XCD a run of n-slices over one m-tile -> A-tile L2 reuse (R7: FETCH 139->51MB).
__device__ __forceinline__ void fc_tile_map(int bid, int nm, int& m_idx, int& n_idx) {
  if ((nm & 7) == 0) {
    int x = bid & 7;
    int k = bid >> 3;              // 0 .. nm*4/8-1
    m_idx = x * (nm >> 3) + (k >> 2);
    n_idx = k & 3;
  } else {
    m_idx = bid >> 2;
    n_idx = bid & 3;
  }
}

// ---------------------------------------------------------------- W transpose (256x128 <- 128x256), fp32
__global__ void k_transpose_w(const float* __restrict__ w, float* __restrict__ wt) {
  int i = blockIdx.x * 256 + threadIdx.x;   // 32768
  int d = i & 127, c = i >> 7;
  wt[c * 128 + d] = w[d * 256 + c];
}

// ---------------------------------------------------------------- FC weight transpose+cast: wt_fp8[n][k] = fp8(w[k][n])
__global__ __launch_bounds__(256) void k_wtrans(const float* __restrict__ w,
                                                unsigned char* __restrict__ wt) {
  __shared__ float tile[32][33];
  int n0 = blockIdx.x * 32, k0 = blockIdx.y * 32;
  int tx = threadIdx.x & 31, ty = threadIdx.x >> 5;   // 32 x 8
#pragma unroll
  for (int r = 0; r < 32; r += 8)
    tile[ty + r][tx] = w[(size_t)(k0 + ty + r) * 1024 + n0 + tx];
  __syncthreads();
#pragma unroll
  for (int r = 0; r < 32; r += 8)
    wt[(size_t)(n0 + ty + r) * 1024 + k0 + tx] = f2fp8(tile[tx][ty + r]);
}

// ---------------------------------------------------------------- loi GEMM (fp32 math, bf16 store): loi_t[b][p][d]
__global__ __launch_bounds__(256) void k_loi(const float* __restrict__ F,
                                             const float* __restrict__ wt,
                                             const float* __restrict__ bias,
                                             unsigned short* __restrict__ loi) {
  int b = blockIdx.y;
  int p0 = blockIdx.x * 64;
  __shared__ float As[8][64];
  __shared__ float Bs[8][128];
  int t = threadIdx.x;
  int tn = t & 15;    // n group: n = tn*8
  int tm = t >> 4;    // m group: m = tm*4
  float acc[4][8];
#pragma unroll
  for (int i = 0; i < 4; ++i)
#pragma unroll
    for (int j = 0; j < 8; ++j) acc[i][j] = 0.0f;

  const float* Fb = F + (size_t)b * 256 * HW;
  for (int c0 = 0; c0 < 256; c0 += 8) {
    __syncthreads();
    if (t < 128) {
      int kk = t >> 4, mv = t & 15;
      float4 v = *(const float4*)(Fb + (size_t)(c0 + kk) * HW + p0 + mv * 4);
      *(float4*)&As[kk][mv * 4] = v;
    }
    {
      int kk = t >> 5, dv = t & 31;
      float4 v = *(const float4*)(wt + (size_t)(c0 + kk) * 128 + dv * 4);
      *(float4*)&Bs[kk][dv * 4] = v;
    }
    __syncthreads();
#pragma unroll
    for (int kk = 0; kk < 8; ++kk) {
      float4 a4 = *(const float4*)&As[kk][tm * 4];
      float4 b0 = *(const float4*)&Bs[kk][tn * 8];
      float4 b1 = *(const float4*)&Bs[kk][tn * 8 + 4];
      float av[4] = {a4.x, a4.y, a4.z, a4.w};
      float bv[8] = {b0.x, b0.y, b0.z, b0.w, b1.x, b1.y, b1.z, b1.w};
#pragma unroll
      for (int i = 0; i < 4; ++i)
#pragma unroll
        for (int j = 0; j < 8; ++j) acc[i][j] += av[i] * bv[j];
    }
  }
  float4 c0v = *(const float4*)(bias + tn * 8);
  float4 c1v = *(const float4*)(bias + tn * 8 + 4);
  float bb[8] = {c0v.x, c0v.y, c0v.z, c0v.w, c1v.x, c1v.y, c1v.z, c1v.w};
#pragma unroll
  for (int i = 0; i < 4; ++i) {
    int p = p0 + tm * 4 + i;
    alignas(16) unsigned short o[8];
#pragma unroll
    for (int j = 0; j < 8; ++j) o[j] = f2bf(acc[i][j] + bb[j]);
    *(s16x8*)(loi + ((size_t)b * HW + p) * 128 + tn * 8) = *(const s16x8*)o;
  }
}

// ---------------------------------------------------------------- jloc = softmax(out9[5:7])[1]
__global__ void k_jloc(const float* __restrict__ out9, float* __restrict__ jloc) {
  int i = blockIdx.x * 256 + threadIdx.x;    // NB*HW
  int b = i >> 14, p = i & (HW - 1);
  const float* base = out9 + (size_t)b * 9 * HW;
  float o5 = base[5 * HW + p], o6 = base[6 * HW + p];
  float m = fmaxf(o5, o6);
  float e5 = expf(o5 - m), e6 = expf(o6 - m);
  jloc[i] = e6 / (e5 + e6);
}

// ---------------------------------------------------------------- NMS + sortable key
__global__ void k_nmskey(const float* __restrict__ jloc, unsigned long long* __restrict__ keys) {
  int i = blockIdx.x * 256 + threadIdx.x;
  int b = i >> 14, p = i & (HW - 1);
  int y = p >> 7, x = p & 127;
  const float* J = jloc + (size_t)b * HW;
  float c = J[p];
  float m = c;
  for (int dy = -1; dy <= 1; ++dy) {
    int yy = y + dy;
    if (yy < 0 || yy > 127) continue;
    for (int dx = -1; dx <= 1; ++dx) {
      int xx = x + dx;
      if (xx < 0 || xx > 127) continue;
      m = fmaxf(m, J[yy * WIDTH + xx]);
    }
  }
  unsigned int vb = (c == m) ? __float_as_uint(c) : 0u;   // jloc > 0 always -> bits monotone
  keys[i] = ((unsigned long long)vb << 32) | (unsigned int)(~p);
}

// ---------------------------------------------------------------- top-300 per image via bitonic sort (1 block/image)
__global__ __launch_bounds__(1024) void k_topk(const unsigned long long* __restrict__ keys,
                                               const float* __restrict__ out9,
                                               float* __restrict__ jx, float* __restrict__ jy) {
  int b = blockIdx.x;
  __shared__ unsigned long long cand[4096];
  __shared__ int cnt;
  int t = threadIdx.x;
  if (t == 0) cnt = 0;
#pragma unroll
  for (int i = t; i < 4096; i += 1024) cand[i] = 0ull;
  __syncthreads();
  const unsigned long long* K = keys + (size_t)b * HW;
  for (int i = t; i < HW; i += 1024) {
    unsigned long long k = K[i];
    if ((k >> 32) != 0ull) {
      int pos = atomicAdd(&cnt, 1);
      if (pos < 4096) cand[pos] = k;
    }
  }
  __syncthreads();
  // bitonic sort, descending (keys distinct except zero-padding)
  for (int k = 2; k <= 4096; k <<= 1) {
    for (int j = k >> 1; j > 0; j >>= 1) {
#pragma unroll
      for (int idx = t; idx < 4096; idx += 1024) {
        int ixj = idx ^ j;
        if (ixj > idx) {
          unsigned long long a = cand[idx], c = cand[ixj];
          bool up = ((idx & k) == 0);
          if (up ? (a < c) : (a > c)) { cand[idx] = c; cand[ixj] = a; }
        }
      }
      __syncthreads();
    }
  }
  if (t < NTOPK) {
    const float* o7 = out9 + (size_t)b * 9 * HW + 7 * HW;
    const float* o8 = out9 + (size_t)b * 9 * HW + 8 * HW;
    unsigned long long bb = cand[t];
    unsigned int vb = (unsigned int)(bb >> 32);
    float val = __uint_as_float(vb);
    if (vb != 0u && val > JUNC_TH) {
      int p = (int)(~((unsigned int)(bb & 0xffffffffull))) & (HW - 1);
      float ox = sigm(o7[p]) - 0.5f;
      float oy = sigm(o8[p]) - 0.5f;
      jx[b * NTOPK + t] = (float)(p & 127) + ox + 0.5f;
      jy[b * NTOPK + t] = (float)(p >> 7) + oy + 0.5f;
    } else {
      jx[b * NTOPK + t] = 1000000.0f;
      jy[b * NTOPK + t] = 1000000.0f;
    }
  }
}

// ---------------------------------------------------------------- per-line argmin assignment + lines2 output
__global__ __launch_bounds__(256) void k_lines(const float* __restrict__ lp,
                                               const float* __restrict__ jx,
                                               const float* __restrict__ jy,
                                               float4* __restrict__ lines4,
                                               int* __restrict__ iskeep,
                                               float* __restrict__ out_lines) {
  int b = blockIdx.y;
  int l = blockIdx.x * 256 + threadIdx.x;
  __shared__ float jxs[NTOPK], jys[NTOPK];
  for (int i = threadIdx.x; i < NTOPK; i += 256) {
    jxs[i] = jx[b * NTOPK + i];
    jys[i] = jy[b * NTOPK + i];
  }
  __syncthreads();
  int gl = b * HW + l;
  const float* L = lp + (size_t)gl * 4;
  float x1 = L[0], y1 = L[1], x2 = L[2], y2 = L[3];
  float bd1 = 3.4e38f, bd2 = 3.4e38f;
  int i1 = 0, i2 = 0;
  for (int j = 0; j < NTOPK; ++j) {
    float ax = __fsub_rn(x1, jxs[j]);
    float ay = __fsub_rn(y1, jys[j]);
    float d1 = __fadd_rn(__fmul_rn(ax, ax), __fmul_rn(ay, ay));
    if (d1 < bd1) { bd1 = d1; i1 = j; }
    float ex = __fsub_rn(x2, jxs[j]);
    float ey = __fsub_rn(y2, jys[j]);
    float d2 = __fadd_rn(__fmul_rn(ex, ex), __fmul_rn(ey, ey));
    if (d2 < bd2) { bd2 = d2; i2 = j; }
  }
  int imin = min(i1, i2), imax = max(i1, i2);
  float sx1 = jxs[imin], sy1 = jys[imin], sx2 = jxs[imax], sy2 = jys[imax];
  lines4[gl] = make_float4(sx1, sy1, sx2, sy2);
  iskeep[gl] = (imin < imax) ? 1 : 0;
  ((float4*)out_lines)[gl] = make_float4(sx1 * 4.0f, sy1 * 4.0f, sx2 * 4.0f, sy2 * 4.0f);
}

// ---------------------------------------------------------------- bilinear sample + maxpool -> xvec fp8
__global__ __launch_bounds__(128) void k_sample(const unsigned short* __restrict__ loi,
                                                const float4* __restrict__ lines4,
                                                unsigned char* __restrict__ xvec,
                                                int b_base, int l0, int rows_per_b) {
  __shared__ int   soff[2][32][4];
  __shared__ float swt[2][32][4];
  int b = b_base + blockIdx.y;
  int t = threadIdx.x;
  if (t < 64) {
    int li = t >> 5, k = t & 31;
    int l = l0 + blockIdx.x * 2 + li;
    float4 ln = lines4[b * HW + l];
    float tt = (float)k * (1.0f / 31.0f);
    float tc = 1.0f - tt;
    float px = ln.x * tt + ln.z * tc - 0.5f;
    float py = ln.y * tt + ln.w * tc - 0.5f;
    float px0 = fminf(fmaxf(floorf(px), 0.0f), 127.0f);
    float py0 = fminf(fmaxf(floorf(py), 0.0f), 127.0f);
    float px1 = fminf(px0 + 1.0f, 127.0f);
    float py1 = fminf(py0 + 1.0f, 127.0f);
    int ix0 = (int)px0, iy0 = (int)py0, ix1 = (int)px1, iy1 = (int)py1;
    float wy1 = __fsub_rn(py1, py), wy0 = __fsub_rn(py, py0);
    float wx1 = __fsub_rn(px1, px), wx0 = __fsub_rn(px, px0);
    soff[li][k][0] = (iy0 * WIDTH + ix0) * 128;
    soff[li][k][1] = (iy1 * WIDTH + ix0) * 128;
    soff[li][k][2] = (iy0 * WIDTH + ix1) * 128;
    soff[li][k][3] = (iy1 * WIDTH + ix1) * 128;
    swt[li][k][0] = __fmul_rn(wy1, wx1);   // wa -> r00
    swt[li][k][1] = __fmul_rn(wy0, wx1);   // wb -> r10
    swt[li][k][2] = __fmul_rn(wy1, wx0);   // wc -> r01
    swt[li][k][3] = __fmul_rn(wy0, wx0);   // wd -> r11
  }
  __syncthreads();
  int li = t >> 6, c2 = t & 63;            // channels 2*c2, 2*c2+1
  int l = l0 + blockIdx.x * 2 + li;
  const unsigned short* Lb = loi + (size_t)b * HW * 128 + (c2 << 1);
  float rm0 = -3.4e38f, rm1 = -3.4e38f;
  float fv[16];
#pragma unroll 4
  for (int k = 0; k < 32; ++k) {
    int4   o = *(const int4*)soff[li][k];
    float4 w = *(const float4*)swt[li][k];
    unsigned int u0 = *(const unsigned int*)(Lb + o.x);
    unsigned int u1 = *(const unsigned int*)(Lb + o.y);
    unsigned int u2 = *(const unsigned int*)(Lb + o.z);
    unsigned int u3 = *(const unsigned int*)(Lb + o.w);
    float2 v0 = bf2x2(u0), v1 = bf2x2(u1), v2 = bf2x2(u2), v3 = bf2x2(u3);
    float a0 = __fadd_rn(__fadd_rn(__fadd_rn(__fmul_rn(v0.x, w.x), __fmul_rn(v1.x, w.y)),
                                   __fmul_rn(v2.x, w.z)), __fmul_rn(v3.x, w.w));
    float a1 = __fadd_rn(__fadd_rn(__fadd_rn(__fmul_rn(v0.y, w.x), __fmul_rn(v1.y, w.y)),
                                   __fmul_rn(v2.y, w.z)), __fmul_rn(v3.y, w.w));
    rm0 = fmaxf(rm0, a0);
    rm1 = fmaxf(rm1, a1);
    if ((k & 3) == 3) {
      fv[k >> 2]     = rm0;
      fv[8 + (k >> 2)] = rm1;
      rm0 = -3.4e38f; rm1 = -3.4e38f;
    }
  }
  int4 pk;
  int d;
  d = __builtin_amdgcn_cvt_pk_fp8_f32(fv[0], fv[1], 0, false);
  d = __builtin_amdgcn_cvt_pk_fp8_f32(fv[2], fv[3], d, true);
  pk.x = d;
  d = __builtin_amdgcn_cvt_pk_fp8_f32(fv[4], fv[5], 0, false);
  d = __builtin_amdgcn_cvt_pk_fp8_f32(fv[6], fv[7], d, true);
  pk.y = d;
  d = __builtin_amdgcn_cvt_pk_fp8_f32(fv[8], fv[9], 0, false);
  d = __builtin_amdgcn_cvt_pk_fp8_f32(fv[10], fv[11], d, true);
  pk.z = d;
  d = __builtin_amdgcn_cvt_pk_fp8_f32(fv[12], fv[13], 0, false);
  d = __builtin_amdgcn_cvt_pk_fp8_f32(fv[14], fv[15], d, true);
  pk.w = d;
  size_t xrow = (size_t)blockIdx.y * rows_per_b + (l - l0);
  *(int4*)(xvec + xrow * 1024 + c2 * 16) = pk;
}

// ---------------------------------------------------------------- shared FC K-loop (fp8): BM=256, BN=256, BK=32, 512 thr / 8 waves.
// A,B staged via global_load_lds (1 GLOAD16 each per wave per iter), dbuf 2x16KB.
// LDS layout: row r of tile at byte r*32 (+8192 for B). Fragment = 8 fp8 (long),
// k = (lane>>4)*8 + j, row = lane&15 (same mapping family as bf16 16x16x32).
__device__ __forceinline__ void fc_kloop(const unsigned char* __restrict__ A,
                                         const unsigned char* __restrict__ Bt,
                                         unsigned char* sm, int m0, int n0,
                                         f32x4 acc[4][8]) {
  const int K = 1024;
  int t = threadIdx.x, lane = t & 63, w = t >> 6;   // w 0..7
  int wm = w & 3, wn = w >> 2;
  int lr = lane & 15, ls = lane >> 4;

  const unsigned char* gA = A + (size_t)(m0 + w * 32 + (lane >> 1)) * K + (lane & 1) * 16;
  const unsigned char* gB = Bt + (size_t)(n0 + w * 32 + (lane >> 1)) * K + (lane & 1) * 16;
  int oA = w * 1024 + lane * 16;
  int oB = 8192 + w * 1024 + lane * 16;

  GLOAD_LDS16(gA, sm + oA);
  GLOAD_LDS16(gB, sm + oB);
  __syncthreads();

  int cur = 0;
  for (int k0 = 0; k0 < K; k0 += 32) {
    int nxt = cur ^ 1;
    if (k0 + 32 < K) {
      unsigned char* d = sm + nxt * 16384;
      GLOAD_LDS16(gA + k0 + 32, d + oA);
      GLOAD_LDS16(gB + k0 + 32, d + oB);
    }
    const unsigned char* As = sm + cur * 16384;
    const unsigned char* Bs = As + 8192;
    long af[4];
#pragma unroll
    for (int mi = 0; mi < 4; ++mi)
      af[mi] = *(const long*)(As + (wm * 64 + mi * 16 + lr) * 32 + ls * 8);
#pragma unroll
    for (int ni = 0; ni < 8; ++ni) {
      long bf = *(const long*)(Bs + (wn * 128 + ni * 16 + lr) * 32 + ls * 8);
#pragma unroll
      for (int mi = 0; mi < 4; ++mi)
        acc[mi][ni] = __builtin_amdgcn_mfma_f32_16x16x32_fp8_fp8(af[mi], bf, acc[mi][ni], 0, 0, 0);
    }
    __syncthreads();
    cur = nxt;
  }
}

// ---------------------------------------------------------------- fc1: C = relu(A @ Bt^T + bias), fp8 out, 256x256 tile
__global__ __launch_bounds__(512, 2) void k_fc1(const unsigned char* __restrict__ A,
                                                const unsigned char* __restrict__ Bt,
                                                const float* __restrict__ bias,
                                                unsigned char* __restrict__ C,
                                                int nm) {
  const int N = 1024;
  __shared__ __align__(16) unsigned char sm[32768];   // dbuf 2x16KB; epilogue 64x272
  int t = threadIdx.x, lane = t & 63, w = t >> 6;
  int wm = w & 3, wn = w >> 2;
  int lr = lane & 15, ls = lane >> 4;
  int m_idx, n_idx;
  fc_tile_map(blockIdx.x, nm, m_idx, n_idx);
  int m0 = m_idx * 256, n0 = n_idx * 256;

  f32x4 acc[4][8];
#pragma unroll
  for (int i = 0; i < 4; ++i)
#pragma unroll
    for (int j = 0; j < 8; ++j) acc[i][j] = (f32x4){0.f, 0.f, 0.f, 0.f};

  fc_kloop(A, Bt, sm, m0, n0, acc);
  __syncthreads();

  // 4-pass LDS-staged epilogue: pass p stages rows [p*64, p*64+64) into 64x272 bytes
  for (int p = 0; p < 4; ++p) {
    if (wm == p) {
#pragma unroll
      for (int ni = 0; ni < 8; ++ni) {
        int cl = wn * 128 + ni * 16 + lr;
        float bv = bias[n0 + cl];
#pragma unroll
        for (int mi = 0; mi < 4; ++mi) {
          int rl = mi * 16 + ls * 4;
#pragma unroll
          for (int r = 0; r < 4; ++r)
            sm[(rl + r) * 272 + cl] = f2fp8(fmaxf(acc[mi][ni][r] + bv, 0.0f));
        }
      }
    }
    __syncthreads();
    {
      int row = t >> 3, seg = t & 7;   // 64 rows x 8 segs of 32 bytes
      const unsigned char* src = sm + row * 272 + seg * 32;
      unsigned char* dst = C + (size_t)(m0 + p * 64 + row) * N + n0 + seg * 32;
      *(int4*)dst        = *(const int4*)src;
      *(int4*)(dst + 16) = *(const int4*)(src + 16);
    }
    __syncthreads();
  }
}

// ---------------------------------------------------------------- fc2 fused with logits: per-n0 partial sums (no atomics)
__global__ __launch_bounds__(512, 2) void k_fc2log(const unsigned char* __restrict__ A,
                                                   const unsigned char* __restrict__ Bt,
                                                   const float* __restrict__ bias,
                                                   const float* __restrict__ w3,
                                                   float* __restrict__ logp,
                                                   int base, int nm) {
  __shared__ __align__(16) unsigned char sm[32768];
  int t = threadIdx.x, lane = t & 63, w = t >> 6;
  int wm = w & 3, wn = w >> 2;
  int lr = lane & 15, ls = lane >> 4;
  int m_idx, n_idx;
  fc_tile_map(blockIdx.x, nm, m_idx, n_idx);
  int m0 = m_idx * 256, n0 = n_idx * 256;

  f32x4 acc[4][8];
#pragma unroll
  for (int i = 0; i < 4; ++i)
#pragma unroll
    for (int j = 0; j < 8; ++j) acc[i][j] = (f32x4){0.f, 0.f, 0.f, 0.f};

  fc_kloop(A, Bt, sm, m0, n0, acc);

  float psum[4][4];
#pragma unroll
  for (int mi = 0; mi < 4; ++mi)
#pragma unroll
    for (int r = 0; r < 4; ++r) psum[mi][r] = 0.0f;
#pragma unroll
  for (int ni = 0; ni < 8; ++ni) {
    int col = n0 + wn * 128 + ni * 16 + lr;
    float bv = bias[col];
    float wv = w3[col];
#pragma unroll
    for (int mi = 0; mi < 4; ++mi)
#pragma unroll
      for (int r = 0; r < 4; ++r)
        psum[mi][r] += fmaxf(acc[mi][ni][r] + bv, 0.0f) * wv;
  }
  __syncthreads();
  float* red = (float*)sm;    // 256 rows x 2 (wn halves)
#pragma unroll
  for (int mi = 0; mi < 4; ++mi)
#pragma unroll
    for (int r = 0; r < 4; ++r) {
      float v = psum[mi][r];
      v += __shfl_xor(v, 1, 64);
      v += __shfl_xor(v, 2, 64);
      v += __shfl_xor(v, 4, 64);
      v += __shfl_xor(v, 8, 64);
      if (lr == 0) {
        int row = wm * 64 + mi * 16 + ls * 4 + r;
        red[row * 2 + wn] = v;
      }
    }
  __syncthreads();
  if (t < 256)
    logp[(size_t)(base + m0 + t) * 4 + n_idx] = red[t * 2] + red[t * 2 + 1];
}

// ---------------------------------------------------------------- final: reduce partials + sigmoid + keep
__global__ __launch_bounds__(256) void k_fin(const float* __restrict__ logp,
                                             const float* __restrict__ b3,
                                             const int* __restrict__ iskeep,
                                             float* __restrict__ oscore,
                                             float* __restrict__ okeep,
                                             int base) {
  int gl = base + blockIdx.x * 256 + threadIdx.x;
  float4 a = ((const float4*)logp)[gl];
  float s = (a.x + a.y) + (a.z + a.w);
  float sc = sigm(s + b3[0]);
  oscore[gl] = sc;
  okeep[gl] = (iskeep[gl] && sc > 0.05f) ? 1.0f : 0.0f;
}

// ================================================================ host
extern "C" void kernel_launch(void* const* d_in, const int* in_sizes, int n_in,
                              void* d_out, int out_size, void* d_ws, size_t ws_size,
                              hipStream_t stream) {
  const float* output     = (const float*)d_in[0];
  const float* features   = (const float*)d_in[1];
  const float* line_preds = (const float*)d_in[2];
  const float* conv_w     = (const float*)d_in[3];
  const float* conv_b     = (const float*)d_in[4];
  const float* w1         = (const float*)d_in[5];
  const float* b1         = (const float*)d_in[6];
  const float* w2         = (const float*)d_in[7];
  const float* b2         = (const float*)d_in[8];
  const float* w3         = (const float*)d_in[9];
  const float* b3         = (const float*)d_in[10];

  char* ws = (char*)d_ws;
  size_t off = 0;
  auto alloc = [&](size_t bytes) -> void* {
    void* p = ws + off;
    off += (bytes + 255) & ~(size_t)255;
    return p;
  };
  float* wt      = (float*)alloc((size_t)256 * 128 * 4);
  unsigned short* loi = (unsigned short*)alloc((size_t)NB * HW * 128 * 2);
  float* jloc    = (float*)alloc((size_t)NB * HW * 4);
  unsigned long long* keys = (unsigned long long*)alloc((size_t)NB * HW * 8);
  float* jx      = (float*)alloc((size_t)NB * NTOPK * 4);
  float* jy      = (float*)alloc((size_t)NB * NTOPK * 4);
  float4* lines4 = (float4*)alloc((size_t)NB * HW * 16);
  int* iskeep    = (int*)alloc((size_t)NB * HW * 4);
  float* logp    = (float*)alloc((size_t)NB * HW * 4 * 4);   // 4 partials per line
  unsigned char* w1b = (unsigned char*)alloc((size_t)1024 * 1024);   // [N][K] fp8
  unsigned char* w2b = (unsigned char*)alloc((size_t)1024 * 1024);
  size_t fixed = off;

  // pick activation size: merged (both images, M=32768) if it fits, else per-image chunks
  bool merged = (fixed + (size_t)2 * NB * HW * 1024 + 512 <= ws_size);
  int CH = 256;
  if (!merged) {
    const int cands[7] = {16384, 8192, 4096, 2048, 1024, 512, 256};
    for (int ci = 0; ci < 7; ++ci) {
      if (fixed + (size_t)2 * cands[ci] * 1024 + 512 <= ws_size) { CH = cands[ci]; break; }
    }
  }
  size_t actrows = merged ? (size_t)NB * HW : (size_t)CH;
  unsigned char* xvec = (unsigned char*)alloc(actrows * 1024);
  unsigned char* h1   = (unsigned char*)alloc(actrows * 1024);

  float* out_lines  = (float*)d_out;              // (B, L, 2, 2)
  float* out_scores = out_lines + (size_t)NB * HW * 4;
  float* out_keep   = out_scores + (size_t)NB * HW;

  k_transpose_w<<<128, 256, 0, stream>>>(conv_w, wt);
  k_wtrans<<<dim3(32, 32), 256, 0, stream>>>(w1, w1b);
  k_wtrans<<<dim3(32, 32), 256, 0, stream>>>(w2, w2b);
  k_loi<<<dim3(HW / 64, NB), 256, 0, stream>>>(features, wt, conv_b, loi);
  k_jloc<<<NB * HW / 256, 256, 0, stream>>>(output, jloc);
  k_nmskey<<<NB * HW / 256, 256, 0, stream>>>(jloc, keys);
  k_topk<<<NB, 1024, 0, stream>>>(keys, output, jx, jy);
  k_lines<<<dim3(HW / 256, NB), 256, 0, stream>>>(line_preds, jx, jy, lines4, iskeep, out_lines);

  if (merged) {
    int M = NB * HW, nm = M / 256;
    k_sample<<<dim3(HW / 2, NB), 128, 0, stream>>>(loi, lines4, xvec, 0, 0, HW);
    k_fc1<<<nm * 4, 512, 0, stream>>>(xvec, w1b, b1, h1, nm);
    k_fc2log<<<nm * 4, 512, 0, stream>>>(h1, w2b, b2, w3, logp, 0, nm);
    k_fin<<<M / 256, 256, 0, stream>>>(logp, b3, iskeep, out_scores, out_keep, 0);
  } else {
    int nchunk = HW / CH, nm = CH / 256;
    for (int b = 0; b < NB; ++b) {
      for (int ci = 0; ci < nchunk; ++ci) {
        int l0 = ci * CH;
        int base = b * HW + l0;
        k_sample<<<dim3(CH / 2, 1), 128, 0, stream>>>(loi, lines4, xvec, b, l0, CH);
        k_fc1<<<nm * 4, 512, 0, stream>>>(xvec, w1b, b1, h1, nm);
        k_fc2log<<<nm * 4, 512, 0, stream>>>(h1, w2b, b2, w3, logp, base, nm);
        k_fin<<<CH / 256, 256, 0, stream>>>(logp, b3, iskeep, out_scores, out_keep, base);
      }
    }
  }
}

// Round 11
// 400.957 us; speedup vs baseline: 1.6380x; 1.0242x over previous
//
#include <hip/hip_runtime.h>
#include <hip/hip_bf16.h>
#include <cstdint>
#include <cstddef>

#define HW     16384      // H*W
#define WIDTH  128
#define NB     2
#define NTOPK  300
#define JUNC_TH 0.008f

typedef __attribute__((ext_vector_type(8))) short s16x8;
typedef __attribute__((ext_vector_type(4))) float f32x4;

// ---------------------------------------------------------------- utilities
__device__ __forceinline__ float sigm(float x) { return 1.0f / (1.0f + expf(-x)); }

__device__ __forceinline__ unsigned short f2bf(float f) {
  __hip_bfloat16 h = __float2bfloat16(f);
  return __hip_bfloat16_raw(h).x;
}
__device__ __forceinline__ float2 bf2x2(unsigned int u) {
  return make_float2(__uint_as_float(u << 16), __uint_as_float(u & 0xffff0000u));
}
// OCP e4m3 conversion via v_cvt_pk_fp8_f32 (gfx950 HW format is OCP)
__device__ __forceinline__ unsigned char f2fp8(float v) {
  return (unsigned char)(__builtin_amdgcn_cvt_pk_fp8_f32(v, 0.0f, 0, false) & 0xff);
}

#define GLOAD_LDS16(gp, lp)                                                        \
  __builtin_amdgcn_global_load_lds((const __attribute__((address_space(1))) void*)(gp), \
                                   (__attribute__((address_space(3))) void*)(lp), 16, 0, 0)

// XCD-cohort swizzle: consecutive blocks round-robin across 8 XCDs; give each
// XCD a run of n-slices over one m-tile -> A-tile L2 reuse (R7: FETCH 139->51MB).
__device__ __forceinline__ void fc_tile_map(int bid, int nm, int& m_idx, int& n_idx) {
  if ((nm & 7) == 0) {
    int x = bid & 7;
    int k = bid >> 3;              // 0 .. nm*4/8-1
    m_idx = x * (nm >> 3) + (k >> 2);
    n_idx = k & 3;
  } else {
    m_idx = bid >> 2;
    n_idx = bid & 3;
  }
}

// ---------------------------------------------------------------- W transpose (256x128 <- 128x256), fp32
__global__ void k_transpose_w(const float* __restrict__ w, float* __restrict__ wt) {
  int i = blockIdx.x * 256 + threadIdx.x;   // 32768
  int d = i & 127, c = i >> 7;
  wt[c * 128 + d] = w[d * 256 + c];
}

// ---------------------------------------------------------------- FC weight transpose+cast: wt_fp8[n][k] = fp8(w[k][n])
__global__ __launch_bounds__(256) void k_wtrans(const float* __restrict__ w,
                                                unsigned char* __restrict__ wt) {
  __shared__ float tile[32][33];
  int n0 = blockIdx.x * 32, k0 = blockIdx.y * 32;
  int tx = threadIdx.x & 31, ty = threadIdx.x >> 5;   // 32 x 8
#pragma unroll
  for (int r = 0; r < 32; r += 8)
    tile[ty + r][tx] = w[(size_t)(k0 + ty + r) * 1024 + n0 + tx];
  __syncthreads();
#pragma unroll
  for (int r = 0; r < 32; r += 8)
    wt[(size_t)(n0 + ty + r) * 1024 + k0 + tx] = f2fp8(tile[tx][ty + r]);
}

// ---------------------------------------------------------------- loi GEMM (fp32 math, bf16 store): loi_t[b][p][d]
__global__ __launch_bounds__(256) void k_loi(const float* __restrict__ F,
                                             const float* __restrict__ wt,
                                             const float* __restrict__ bias,
                                             unsigned short* __restrict__ loi) {
  int b = blockIdx.y;
  int p0 = blockIdx.x * 64;
  __shared__ float As[8][64];
  __shared__ float Bs[8][128];
  int t = threadIdx.x;
  int tn = t & 15;    // n group: n = tn*8
  int tm = t >> 4;    // m group: m = tm*4
  float acc[4][8];
#pragma unroll
  for (int i = 0; i < 4; ++i)
#pragma unroll
    for (int j = 0; j < 8; ++j) acc[i][j] = 0.0f;

  const float* Fb = F + (size_t)b * 256 * HW;
  for (int c0 = 0; c0 < 256; c0 += 8) {
    __syncthreads();
    if (t < 128) {
      int kk = t >> 4, mv = t & 15;
      float4 v = *(const float4*)(Fb + (size_t)(c0 + kk) * HW + p0 + mv * 4);
      *(float4*)&As[kk][mv * 4] = v;
    }
    {
      int kk = t >> 5, dv = t & 31;
      float4 v = *(const float4*)(wt + (size_t)(c0 + kk) * 128 + dv * 4);
      *(float4*)&Bs[kk][dv * 4] = v;
    }
    __syncthreads();
#pragma unroll
    for (int kk = 0; kk < 8; ++kk) {
      float4 a4 = *(const float4*)&As[kk][tm * 4];
      float4 b0 = *(const float4*)&Bs[kk][tn * 8];
      float4 b1 = *(const float4*)&Bs[kk][tn * 8 + 4];
      float av[4] = {a4.x, a4.y, a4.z, a4.w};
      float bv[8] = {b0.x, b0.y, b0.z, b0.w, b1.x, b1.y, b1.z, b1.w};
#pragma unroll
      for (int i = 0; i < 4; ++i)
#pragma unroll
        for (int j = 0; j < 8; ++j) acc[i][j] += av[i] * bv[j];
    }
  }
  float4 c0v = *(const float4*)(bias + tn * 8);
  float4 c1v = *(const float4*)(bias + tn * 8 + 4);
  float bb[8] = {c0v.x, c0v.y, c0v.z, c0v.w, c1v.x, c1v.y, c1v.z, c1v.w};
#pragma unroll
  for (int i = 0; i < 4; ++i) {
    int p = p0 + tm * 4 + i;
    alignas(16) unsigned short o[8];
#pragma unroll
    for (int j = 0; j < 8; ++j) o[j] = f2bf(acc[i][j] + bb[j]);
    *(s16x8*)(loi + ((size_t)b * HW + p) * 128 + tn * 8) = *(const s16x8*)o;
  }
}

// ---------------------------------------------------------------- jloc = softmax(out9[5:7])[1]
__global__ void k_jloc(const float* __restrict__ out9, float* __restrict__ jloc) {
  int i = blockIdx.x * 256 + threadIdx.x;    // NB*HW
  int b = i >> 14, p = i & (HW - 1);
  const float* base = out9 + (size_t)b * 9 * HW;
  float o5 = base[5 * HW + p], o6 = base[6 * HW + p];
  float m = fmaxf(o5, o6);
  float e5 = expf(o5 - m), e6 = expf(o6 - m);
  jloc[i] = e6 / (e5 + e6);
}

// ---------------------------------------------------------------- NMS + sortable key
__global__ void k_nmskey(const float* __restrict__ jloc, unsigned long long* __restrict__ keys) {
  int i = blockIdx.x * 256 + threadIdx.x;
  int b = i >> 14, p = i & (HW - 1);
  int y = p >> 7, x = p & 127;
  const float* J = jloc + (size_t)b * HW;
  float c = J[p];
  float m = c;
  for (int dy = -1; dy <= 1; ++dy) {
    int yy = y + dy;
    if (yy < 0 || yy > 127) continue;
    for (int dx = -1; dx <= 1; ++dx) {
      int xx = x + dx;
      if (xx < 0 || xx > 127) continue;
      m = fmaxf(m, J[yy * WIDTH + xx]);
    }
  }
  unsigned int vb = (c == m) ? __float_as_uint(c) : 0u;   // jloc > 0 always -> bits monotone
  keys[i] = ((unsigned long long)vb << 32) | (unsigned int)(~p);
}

// ---------------------------------------------------------------- top-300 per image via bitonic sort (1 block/image)
__global__ __launch_bounds__(1024) void k_topk(const unsigned long long* __restrict__ keys,
                                               const float* __restrict__ out9,
                                               float* __restrict__ jx, float* __restrict__ jy) {
  int b = blockIdx.x;
  __shared__ unsigned long long cand[4096];
  __shared__ int cnt;
  int t = threadIdx.x;
  if (t == 0) cnt = 0;
#pragma unroll
  for (int i = t; i < 4096; i += 1024) cand[i] = 0ull;
  __syncthreads();
  const unsigned long long* K = keys + (size_t)b * HW;
  for (int i = t; i < HW; i += 1024) {
    unsigned long long k = K[i];
    if ((k >> 32) != 0ull) {
      int pos = atomicAdd(&cnt, 1);
      if (pos < 4096) cand[pos] = k;
    }
  }
  __syncthreads();
  // bitonic sort, descending (keys distinct except zero-padding)
  for (int k = 2; k <= 4096; k <<= 1) {
    for (int j = k >> 1; j > 0; j >>= 1) {
#pragma unroll
      for (int idx = t; idx < 4096; idx += 1024) {
        int ixj = idx ^ j;
        if (ixj > idx) {
          unsigned long long a = cand[idx], c = cand[ixj];
          bool up = ((idx & k) == 0);
          if (up ? (a < c) : (a > c)) { cand[idx] = c; cand[ixj] = a; }
        }
      }
      __syncthreads();
    }
  }
  if (t < NTOPK) {
    const float* o7 = out9 + (size_t)b * 9 * HW + 7 * HW;
    const float* o8 = out9 + (size_t)b * 9 * HW + 8 * HW;
    unsigned long long bb = cand[t];
    unsigned int vb = (unsigned int)(bb >> 32);
    float val = __uint_as_float(vb);
    if (vb != 0u && val > JUNC_TH) {
      int p = (int)(~((unsigned int)(bb & 0xffffffffull))) & (HW - 1);
      float ox = sigm(o7[p]) - 0.5f;
      float oy = sigm(o8[p]) - 0.5f;
      jx[b * NTOPK + t] = (float)(p & 127) + ox + 0.5f;
      jy[b * NTOPK + t] = (float)(p >> 7) + oy + 0.5f;
    } else {
      jx[b * NTOPK + t] = 1000000.0f;
      jy[b * NTOPK + t] = 1000000.0f;
    }
  }
}

// ---------------------------------------------------------------- per-line argmin assignment + lines2 output
__global__ __launch_bounds__(256) void k_lines(const float* __restrict__ lp,
                                               const float* __restrict__ jx,
                                               const float* __restrict__ jy,
                                               float4* __restrict__ lines4,
                                               int* __restrict__ iskeep,
                                               float* __restrict__ out_lines) {
  int b = blockIdx.y;
  int l = blockIdx.x * 256 + threadIdx.x;
  __shared__ float jxs[NTOPK], jys[NTOPK];
  for (int i = threadIdx.x; i < NTOPK; i += 256) {
    jxs[i] = jx[b * NTOPK + i];
    jys[i] = jy[b * NTOPK + i];
  }
  __syncthreads();
  int gl = b * HW + l;
  const float* L = lp + (size_t)gl * 4;
  float x1 = L[0], y1 = L[1], x2 = L[2], y2 = L[3];
  float bd1 = 3.4e38f, bd2 = 3.4e38f;
  int i1 = 0, i2 = 0;
  for (int j = 0; j < NTOPK; ++j) {
    float ax = __fsub_rn(x1, jxs[j]);
    float ay = __fsub_rn(y1, jys[j]);
    float d1 = __fadd_rn(__fmul_rn(ax, ax), __fmul_rn(ay, ay));
    if (d1 < bd1) { bd1 = d1; i1 = j; }
    float ex = __fsub_rn(x2, jxs[j]);
    float ey = __fsub_rn(y2, jys[j]);
    float d2 = __fadd_rn(__fmul_rn(ex, ex), __fmul_rn(ey, ey));
    if (d2 < bd2) { bd2 = d2; i2 = j; }
  }
  int imin = min(i1, i2), imax = max(i1, i2);
  float sx1 = jxs[imin], sy1 = jys[imin], sx2 = jxs[imax], sy2 = jys[imax];
  lines4[gl] = make_float4(sx1, sy1, sx2, sy2);
  iskeep[gl] = (imin < imax) ? 1 : 0;
  ((float4*)out_lines)[gl] = make_float4(sx1 * 4.0f, sy1 * 4.0f, sx2 * 4.0f, sy2 * 4.0f);
}

// ---------------------------------------------------------------- bilinear sample + maxpool -> xvec fp8
__global__ __launch_bounds__(128) void k_sample(const unsigned short* __restrict__ loi,
                                                const float4* __restrict__ lines4,
                                                unsigned char* __restrict__ xvec,
                                                int b_base, int l0, int rows_per_b) {
  __shared__ int   soff[2][32][4];
  __shared__ float swt[2][32][4];
  int b = b_base + blockIdx.y;
  int t = threadIdx.x;
  if (t < 64) {
    int li = t >> 5, k = t & 31;
    int l = l0 + blockIdx.x * 2 + li;
    float4 ln = lines4[b * HW + l];
    float tt = (float)k * (1.0f / 31.0f);
    float tc = 1.0f - tt;
    float px = ln.x * tt + ln.z * tc - 0.5f;
    float py = ln.y * tt + ln.w * tc - 0.5f;
    float px0 = fminf(fmaxf(floorf(px), 0.0f), 127.0f);
    float py0 = fminf(fmaxf(floorf(py), 0.0f), 127.0f);
    float px1 = fminf(px0 + 1.0f, 127.0f);
    float py1 = fminf(py0 + 1.0f, 127.0f);
    int ix0 = (int)px0, iy0 = (int)py0, ix1 = (int)px1, iy1 = (int)py1;
    float wy1 = __fsub_rn(py1, py), wy0 = __fsub_rn(py, py0);
    float wx1 = __fsub_rn(px1, px), wx0 = __fsub_rn(px, px0);
    soff[li][k][0] = (iy0 * WIDTH + ix0) * 128;
    soff[li][k][1] = (iy1 * WIDTH + ix0) * 128;
    soff[li][k][2] = (iy0 * WIDTH + ix1) * 128;
    soff[li][k][3] = (iy1 * WIDTH + ix1) * 128;
    swt[li][k][0] = __fmul_rn(wy1, wx1);   // wa -> r00
    swt[li][k][1] = __fmul_rn(wy0, wx1);   // wb -> r10
    swt[li][k][2] = __fmul_rn(wy1, wx0);   // wc -> r01
    swt[li][k][3] = __fmul_rn(wy0, wx0);   // wd -> r11
  }
  __syncthreads();
  int li = t >> 6, c2 = t & 63;            // channels 2*c2, 2*c2+1
  int l = l0 + blockIdx.x * 2 + li;
  const unsigned short* Lb = loi + (size_t)b * HW * 128 + (c2 << 1);
  float rm0 = -3.4e38f, rm1 = -3.4e38f;
  float fv[16];
#pragma unroll 4
  for (int k = 0; k < 32; ++k) {
    int4   o = *(const int4*)soff[li][k];
    float4 w = *(const float4*)swt[li][k];
    unsigned int u0 = *(const unsigned int*)(Lb + o.x);
    unsigned int u1 = *(const unsigned int*)(Lb + o.y);
    unsigned int u2 = *(const unsigned int*)(Lb + o.z);
    unsigned int u3 = *(const unsigned int*)(Lb + o.w);
    float2 v0 = bf2x2(u0), v1 = bf2x2(u1), v2 = bf2x2(u2), v3 = bf2x2(u3);
    float a0 = __fadd_rn(__fadd_rn(__fadd_rn(__fmul_rn(v0.x, w.x), __fmul_rn(v1.x, w.y)),
                                   __fmul_rn(v2.x, w.z)), __fmul_rn(v3.x, w.w));
    float a1 = __fadd_rn(__fadd_rn(__fadd_rn(__fmul_rn(v0.y, w.x), __fmul_rn(v1.y, w.y)),
                                   __fmul_rn(v2.y, w.z)), __fmul_rn(v3.y, w.w));
    rm0 = fmaxf(rm0, a0);
    rm1 = fmaxf(rm1, a1);
    if ((k & 3) == 3) {
      fv[k >> 2]     = rm0;
      fv[8 + (k >> 2)] = rm1;
      rm0 = -3.4e38f; rm1 = -3.4e38f;
    }
  }
  int4 pk;
  int d;
  d = __builtin_amdgcn_cvt_pk_fp8_f32(fv[0], fv[1], 0, false);
  d = __builtin_amdgcn_cvt_pk_fp8_f32(fv[2], fv[3], d, true);
  pk.x = d;
  d = __builtin_amdgcn_cvt_pk_fp8_f32(fv[4], fv[5], 0, false);
  d = __builtin_amdgcn_cvt_pk_fp8_f32(fv[6], fv[7], d, true);
  pk.y = d;
  d = __builtin_amdgcn_cvt_pk_fp8_f32(fv[8], fv[9], 0, false);
  d = __builtin_amdgcn_cvt_pk_fp8_f32(fv[10], fv[11], d, true);
  pk.z = d;
  d = __builtin_amdgcn_cvt_pk_fp8_f32(fv[12], fv[13], 0, false);
  d = __builtin_amdgcn_cvt_pk_fp8_f32(fv[14], fv[15], d, true);
  pk.w = d;
  size_t xrow = (size_t)blockIdx.y * rows_per_b + (l - l0);
  *(int4*)(xvec + xrow * 1024 + c2 * 16) = pk;
}

// ---------------------------------------------------------------- shared FC K-loop (fp8): BM=256, BN=256, BK=32, 512 thr / 8 waves.
// Staging: lane j loads row (j&31) of the wave's 32-row region, k-chunk (j>>5).
// Resulting LDS image puts fragment (row, ls) at
//   (row>>5)*1024 + (ls>>1)*512 + (row&31)*16 + (ls&1)*8
// -> quarter-wave reads stride 16B = 2-way bank aliasing (free, m136).
// (R10's row*32 layout was 4-way -> 1.9e7 SQ_LDS_BANK_CONFLICT.)
__device__ __forceinline__ void fc_kloop(const unsigned char* __restrict__ A,
                                         const unsigned char* __restrict__ Bt,
                                         unsigned char* sm, int m0, int n0,
                                         f32x4 acc[4][8]) {
  const int K = 1024;
  int t = threadIdx.x, lane = t & 63, w = t >> 6;   // w 0..7
  int wm = w & 3, wn = w >> 2;
  int lr = lane & 15, ls = lane >> 4;

  const unsigned char* gA = A + (size_t)(m0 + w * 32 + (lane & 31)) * K + (lane >> 5) * 16;
  const unsigned char* gB = Bt + (size_t)(n0 + w * 32 + (lane & 31)) * K + (lane >> 5) * 16;
  int oA = w * 1024 + lane * 16;
  int oB = 8192 + w * 1024 + lane * 16;

  // read offsets: c_off = k-seg part; per-fragment row-dependent part precomputed
  int c_off = (ls >> 1) * 512 + (ls & 1) * 8;
  int offA[4], offB[8];
#pragma unroll
  for (int mi = 0; mi < 4; ++mi)
    offA[mi] = (wm * 2 + (mi >> 1)) * 1024 + ((mi & 1) * 16 + lr) * 16 + c_off;
#pragma unroll
  for (int ni = 0; ni < 8; ++ni)
    offB[ni] = 8192 + (wn * 4 + (ni >> 1)) * 1024 + ((ni & 1) * 16 + lr) * 16 + c_off;

  GLOAD_LDS16(gA, sm + oA);
  GLOAD_LDS16(gB, sm + oB);
  __syncthreads();

  int cur = 0;
  for (int k0 = 0; k0 < K; k0 += 32) {
    int nxt = cur ^ 1;
    if (k0 + 32 < K) {
      unsigned char* d = sm + nxt * 16384;
      GLOAD_LDS16(gA + k0 + 32, d + oA);
      GLOAD_LDS16(gB + k0 + 32, d + oB);
    }
    const unsigned char* As = sm + cur * 16384;
    long af[4];
#pragma unroll
    for (int mi = 0; mi < 4; ++mi)
      af[mi] = *(const long*)(As + offA[mi]);
#pragma unroll
    for (int ni = 0; ni < 8; ++ni) {
      long bf = *(const long*)(As + offB[ni]);
#pragma unroll
      for (int mi = 0; mi < 4; ++mi)
        acc[mi][ni] = __builtin_amdgcn_mfma_f32_16x16x32_fp8_fp8(af[mi], bf, acc[mi][ni], 0, 0, 0);
    }
    __syncthreads();
    cur = nxt;
  }
}

// ---------------------------------------------------------------- fc1: C = relu(A @ Bt^T + bias), fp8 out, 256x256 tile
__global__ __launch_bounds__(512, 2) void k_fc1(const unsigned char* __restrict__ A,
                                                const unsigned char* __restrict__ Bt,
                                                const float* __restrict__ bias,
                                                unsigned char* __restrict__ C,
                                                int nm) {
  const int N = 1024;
  __shared__ __align__(16) unsigned char sm[32768];   // dbuf 2x16KB; epilogue 64x272
  int t = threadIdx.x, lane = t & 63, w = t >> 6;
  int wm = w & 3, wn = w >> 2;
  int lr = lane & 15, ls = lane >> 4;
  int m_idx, n_idx;
  fc_tile_map(blockIdx.x, nm, m_idx, n_idx);
  int m0 = m_idx * 256, n0 = n_idx * 256;

  f32x4 acc[4][8];
#pragma unroll
  for (int i = 0; i < 4; ++i)
#pragma unroll
    for (int j = 0; j < 8; ++j) acc[i][j] = (f32x4){0.f, 0.f, 0.f, 0.f};

  fc_kloop(A, Bt, sm, m0, n0, acc);
  __syncthreads();

  // 4-pass LDS-staged epilogue: pass p stages rows [p*64, p*64+64) into 64x272 bytes
  for (int p = 0; p < 4; ++p) {
    if (wm == p) {
#pragma unroll
      for (int ni = 0; ni < 8; ++ni) {
        int cl = wn * 128 + ni * 16 + lr;
        float bv = bias[n0 + cl];
#pragma unroll
        for (int mi = 0; mi < 4; ++mi) {
          int rl = mi * 16 + ls * 4;
#pragma unroll
          for (int r = 0; r < 4; ++r)
            sm[(rl + r) * 272 + cl] = f2fp8(fmaxf(acc[mi][ni][r] + bv, 0.0f));
        }
      }
    }
    __syncthreads();
    {
      int row = t >> 3, seg = t & 7;   // 64 rows x 8 segs of 32 bytes
      const unsigned char* src = sm + row * 272 + seg * 32;
      unsigned char* dst = C + (size_t)(m0 + p * 64 + row) * N + n0 + seg * 32;
      *(int4*)dst        = *(const int4*)src;
      *(int4*)(dst + 16) = *(const int4*)(src + 16);
    }
    __syncthreads();
  }
}

// ---------------------------------------------------------------- fc2 fused with logits: per-n0 partial sums (no atomics)
__global__ __launch_bounds__(512, 2) void k_fc2log(const unsigned char* __restrict__ A,
                                                   const unsigned char* __restrict__ Bt,
                                                   const float* __restrict__ bias,
                                                   const float* __restrict__ w3,
                                                   float* __restrict__ logp,
                                                   int base, int nm) {
  __shared__ __align__(16) unsigned char sm[32768];
  int t = threadIdx.x, lane = t & 63, w = t >> 6;
  int wm = w & 3, wn = w >> 2;
  int lr = lane & 15, ls = lane >> 4;
  int m_idx, n_idx;
  fc_tile_map(blockIdx.x, nm, m_idx, n_idx);
  int m0 = m_idx * 256, n0 = n_idx * 256;

  f32x4 acc[4][8];
#pragma unroll
  for (int i = 0; i < 4; ++i)
#pragma unroll
    for (int j = 0; j < 8; ++j) acc[i][j] = (f32x4){0.f, 0.f, 0.f, 0.f};

  fc_kloop(A, Bt, sm, m0, n0, acc);

  float psum[4][4];
#pragma unroll
  for (int mi = 0; mi < 4; ++mi)
#pragma unroll
    for (int r = 0; r < 4; ++r) psum[mi][r] = 0.0f;
#pragma unroll
  for (int ni = 0; ni < 8; ++ni) {
    int col = n0 + wn * 128 + ni * 16 + lr;
    float bv = bias[col];
    float wv = w3[col];
#pragma unroll
    for (int mi = 0; mi < 4; ++mi)
#pragma unroll
      for (int r = 0; r < 4; ++r)
        psum[mi][r] += fmaxf(acc[mi][ni][r] + bv, 0.0f) * wv;
  }
  __syncthreads();
  float* red = (float*)sm;    // 256 rows x 2 (wn halves)
#pragma unroll
  for (int mi = 0; mi < 4; ++mi)
#pragma unroll
    for (int r = 0; r < 4; ++r) {
      float v = psum[mi][r];
      v += __shfl_xor(v, 1, 64);
      v += __shfl_xor(v, 2, 64);
      v += __shfl_xor(v, 4, 64);
      v += __shfl_xor(v, 8, 64);
      if (lr == 0) {
        int row = wm * 64 + mi * 16 + ls * 4 + r;
        red[row * 2 + wn] = v;
      }
    }
  __syncthreads();
  if (t < 256)
    logp[(size_t)(base + m0 + t) * 4 + n_idx] = red[t * 2] + red[t * 2 + 1];
}

// ---------------------------------------------------------------- final: reduce partials + sigmoid + keep
__global__ __launch_bounds__(256) void k_fin(const float* __restrict__ logp,
                                             const float* __restrict__ b3,
                                             const int* __restrict__ iskeep,
                                             float* __restrict__ oscore,
                                             float* __restrict__ okeep,
                                             int base) {
  int gl = base + blockIdx.x * 256 + threadIdx.x;
  float4 a = ((const float4*)logp)[gl];
  float s = (a.x + a.y) + (a.z + a.w);
  float sc = sigm(s + b3[0]);
  oscore[gl] = sc;
  okeep[gl] = (iskeep[gl] && sc > 0.05f) ? 1.0f : 0.0f;
}

// ================================================================ host
extern "C" void kernel_launch(void* const* d_in, const int* in_sizes, int n_in,
                              void* d_out, int out_size, void* d_ws, size_t ws_size,
                              hipStream_t stream) {
  const float* output     = (const float*)d_in[0];
  const float* features   = (const float*)d_in[1];
  const float* line_preds = (const float*)d_in[2];
  const float* conv_w     = (const float*)d_in[3];
  const float* conv_b     = (const float*)d_in[4];
  const float* w1         = (const float*)d_in[5];
  const float* b1         = (const float*)d_in[6];
  const float* w2         = (const float*)d_in[7];
  const float* b2         = (const float*)d_in[8];
  const float* w3         = (const float*)d_in[9];
  const float* b3         = (const float*)d_in[10];

  char* ws = (char*)d_ws;
  size_t off = 0;
  auto alloc = [&](size_t bytes) -> void* {
    void* p = ws + off;
    off += (bytes + 255) & ~(size_t)255;
    return p;
  };
  float* wt      = (float*)alloc((size_t)256 * 128 * 4);
  unsigned short* loi = (unsigned short*)alloc((size_t)NB * HW * 128 * 2);
  float* jloc    = (float*)alloc((size_t)NB * HW * 4);
  unsigned long long* keys = (unsigned long long*)alloc((size_t)NB * HW * 8);
  float* jx      = (float*)alloc((size_t)NB * NTOPK * 4);
  float* jy      = (float*)alloc((size_t)NB * NTOPK * 4);
  float4* lines4 = (float4*)alloc((size_t)NB * HW * 16);
  int* iskeep    = (int*)alloc((size_t)NB * HW * 4);
  float* logp    = (float*)alloc((size_t)NB * HW * 4 * 4);   // 4 partials per line
  unsigned char* w1b = (unsigned char*)alloc((size_t)1024 * 1024);   // [N][K] fp8
  unsigned char* w2b = (unsigned char*)alloc((size_t)1024 * 1024);
  size_t fixed = off;

  // pick activation size: merged (both images, M=32768) if it fits, else per-image chunks
  bool merged = (fixed + (size_t)2 * NB * HW * 1024 + 512 <= ws_size);
  int CH = 256;
  if (!merged) {
    const int cands[7] = {16384, 8192, 4096, 2048, 1024, 512, 256};
    for (int ci = 0; ci < 7; ++ci) {
      if (fixed + (size_t)2 * cands[ci] * 1024 + 512 <= ws_size) { CH = cands[ci]; break; }
    }
  }
  size_t actrows = merged ? (size_t)NB * HW : (size_t)CH;
  unsigned char* xvec = (unsigned char*)alloc(actrows * 1024);
  unsigned char* h1   = (unsigned char*)alloc(actrows * 1024);

  float* out_lines  = (float*)d_out;              // (B, L, 2, 2)
  float* out_scores = out_lines + (size_t)NB * HW * 4;
  float* out_keep   = out_scores + (size_t)NB * HW;

  k_transpose_w<<<128, 256, 0, stream>>>(conv_w, wt);
  k_wtrans<<<dim3(32, 32), 256, 0, stream>>>(w1, w1b);
  k_wtrans<<<dim3(32, 32), 256, 0, stream>>>(w2, w2b);
  k_loi<<<dim3(HW / 64, NB), 256, 0, stream>>>(features, wt, conv_b, loi);
  k_jloc<<<NB * HW / 256, 256, 0, stream>>>(output, jloc);
  k_nmskey<<<NB * HW / 256, 256, 0, stream>>>(jloc, keys);
  k_topk<<<NB, 1024, 0, stream>>>(keys, output, jx, jy);
  k_lines<<<dim3(HW / 256, NB), 256, 0, stream>>>(line_preds, jx, jy, lines4, iskeep, out_lines);

  if (merged) {
    int M = NB * HW, nm = M / 256;
    k_sample<<<dim3(HW / 2, NB), 128, 0, stream>>>(loi, lines4, xvec, 0, 0, HW);
    k_fc1<<<nm * 4, 512, 0, stream>>>(xvec, w1b, b1, h1, nm);
    k_fc2log<<<nm * 4, 512, 0, stream>>>(h1, w2b, b2, w3, logp, 0, nm);
    k_fin<<<M / 256, 256, 0, stream>>>(logp, b3, iskeep, out_scores, out_keep, 0);
  } else {
    int nchunk = HW / CH, nm = CH / 256;
    for (int b = 0; b < NB; ++b) {
      for (int ci = 0; ci < nchunk; ++ci) {
        int l0 = ci * CH;
        int base = b * HW + l0;
        k_sample<<<dim3(CH / 2, 1), 128, 0, stream>>>(loi, lines4, xvec, b, l0, CH);
        k_fc1<<<nm * 4, 512, 0, stream>>>(xvec, w1b, b1, h1, nm);
        k_fc2log<<<nm * 4, 512, 0, stream>>>(h1, w2b, b2, w3, logp, base, nm);
        k_fin<<<CH / 256, 256, 0, stream>>>(logp, b3, iskeep, out_scores, out_keep, base);
      }
    }
  }
}